// Round 8
// baseline (350.196 us; speedup 1.0000x reference)
//
#include <hip/hip_runtime.h>

#define N_NODES 20000
#define N_EDGES 200000
#define HID 128
#define STR 136   // LDS row stride in u16: 272B rows -> every b128 access 16B-aligned
#define NBLK 3125 // 64-edge tiles

typedef unsigned short u16;
using bf16x8 = __attribute__((ext_vector_type(8))) __bf16;
using f32x4  = __attribute__((ext_vector_type(4))) float;

__device__ __forceinline__ u16 f2bf(float f) {
  union { float f; unsigned u; } v; v.f = f;
  unsigned u = v.u;
  return (u16)((u + 0x7FFFu + ((u >> 16) & 1u)) >> 16);
}
__device__ __forceinline__ float bf2f(unsigned s) {
  union { unsigned u; float f; } v; v.u = s << 16;
  return v.f;
}
__device__ __forceinline__ bf16x8 ld8(const u16* p) { return *(const bf16x8*)p; }

__device__ __forceinline__ void zero_acc(f32x4 acc[4][2]) {
#pragma unroll
  for (int i = 0; i < 4; ++i) {
    acc[i][0] = (f32x4){0.f, 0.f, 0.f, 0.f};
    acc[i][1] = (f32x4){0.f, 0.f, 0.f, 0.f};
  }
}

// GEMM: D[64 edges][128 ch] += A(edges, via afrag)[64][K] * B(packed W)[K][128].
// Wave w owns n-tiles {2w,2w+1}. Depth-2 explicit B prefetch ring hides L2 latency.
template <int KSTEPS, typename AF>
__device__ __forceinline__ void wgemm(const u16* __restrict__ PW, AF afrag,
                                      f32x4 acc[4][2], int lane, int wave) {
  const u16* pb = PW + (wave * 2 * 64 + lane) * 8;
  bf16x8 b0[2], b1[2];
  b0[0] = ld8(pb);
  b1[0] = ld8(pb + 512);
#pragma unroll
  for (int ks = 0; ks < KSTEPS; ++ks) {
    const int cur = ks & 1, nxt = cur ^ 1;
    if (ks + 1 < KSTEPS) {
      b0[nxt] = ld8(pb + (ks + 1) * 4096);
      b1[nxt] = ld8(pb + (ks + 1) * 4096 + 512);
    }
#pragma unroll
    for (int mt = 0; mt < 4; ++mt) {
      bf16x8 a = afrag(ks, mt);
      acc[mt][0] = __builtin_amdgcn_mfma_f32_16x16x32_bf16(a, b0[cur], acc[mt][0], 0, 0, 0);
      acc[mt][1] = __builtin_amdgcn_mfma_f32_16x16x32_bf16(a, b1[cur], acc[mt][1], 0, 0, 0);
    }
  }
}

// C/D: row(edge) = mt*16 + (lane>>4)*4 + r, col(ch) = wave*32 + nt*16 + (lane&15).
template <bool RELU>
__device__ __forceinline__ void epi_store(u16* buf, const f32x4 acc[4][2],
                                          const float* __restrict__ bias,
                                          int lane, int wave) {
  const int c = lane & 15, q = lane >> 4;
  const float bb0 = bias[wave * 32 + c], bb1 = bias[wave * 32 + 16 + c];
#pragma unroll
  for (int mt = 0; mt < 4; ++mt)
#pragma unroll
    for (int nt = 0; nt < 2; ++nt) {
      const float bb = nt ? bb1 : bb0;
      const int col = wave * 32 + nt * 16 + c;
#pragma unroll
      for (int r = 0; r < 4; ++r) {
        float v = acc[mt][nt][r] + bb;
        if (RELU) v = fmaxf(v, 0.f);
        buf[(mt * 16 + q * 4 + r) * STR + col] = f2bf(v);
      }
    }
}

__device__ __forceinline__ void flush_buf(const u16* buf, u16* __restrict__ gout,
                                          int e0, int tid) {
#pragma unroll
  for (int it = 0; it < 4; ++it) {
    int cid = tid + it * 256, e = cid >> 4, p = cid & 15;
    uint4 v = *(const uint4*)(buf + e * STR + p * 8);
    *(uint4*)(gout + (size_t)(e0 + e) * HID + p * 8) = v;
  }
}

// TA-friendly gather: 16 lanes cooperate per row (4 rows x 16 pieces per instr
// -> 8 distinct cache lines, not 64). Covers 128 rows (64 row-gathers -> B0,
// 64 col-gathers -> B1).
__device__ __forceinline__ void stage_gather(const int* __restrict__ rowI,
                                             const int* __restrict__ colI,
                                             const u16* __restrict__ htab,
                                             u16* B0, u16* B1,
                                             int e0, int lane, int wave) {
  const int r = lane >> 4, p = lane & 15;
#pragma unroll
  for (int it = 0; it < 8; ++it) {
    int j = wave * 32 + it * 4 + r;  // 0..127
    int e = j & 63;
    int id = (j < 64) ? rowI[e0 + e] : colI[e0 + e];
    uint4 v = *(const uint4*)(htab + (size_t)id * HID + p * 8);
    *(uint4*)(((j < 64) ? B0 : B1) + e * STR + p * 8) = v;
  }
}

// ---- fold encoder (conv1d+mean+fuse) into M[128x20], C0, Wnt; also b67 ----
__global__ void k_fold(const float* __restrict__ emb, const float* __restrict__ conv_w,
                       const float* __restrict__ conv_b, const float* __restrict__ fuse_w,
                       const float* __restrict__ fuse_b,
                       const float* __restrict__ fm_w1, const float* __restrict__ g2e_b2,
                       const float* __restrict__ fm_b1,
                       float* __restrict__ Mt, float* __restrict__ C0,
                       float* __restrict__ Wnt, float* __restrict__ b67) {
  __shared__ float Ash[128][21];
  int o = threadIdx.x;  // 128 threads
  {
    float b0 = conv_b[o];
#pragma unroll
    for (int p = 0; p < 5; ++p) {
#pragma unroll
      for (int i = 0; i < 8; ++i) {
        float s = 0.f;
#pragma unroll
        for (int k = 0; k < 3; ++k) {
          int t = p + 1 - k;
          if (t >= 0 && t < 5) s += conv_w[(o * 8 + i) * 3 + k];
        }
        s *= 0.2f;
        if (i < 4) Ash[o][p * 4 + i] = s;
        else b0 += emb[p * 4 + (i - 4)] * s;
      }
    }
    Ash[o][20] = b0;
  }
  __syncthreads();
  float m[20];
#pragma unroll
  for (int qq = 0; qq < 20; ++qq) m[qq] = 0.f;
  float c0 = fuse_b[o];
  for (int j = 0; j < 128; ++j) {
    float w = fuse_w[o * 129 + j];
#pragma unroll
    for (int qq = 0; qq < 20; ++qq) m[qq] += w * Ash[j][qq];
    c0 += w * Ash[j][20];
  }
#pragma unroll
  for (int qq = 0; qq < 20; ++qq) Mt[qq * 128 + o] = m[qq];
  C0[o] = c0;
  Wnt[o] = fuse_w[o * 129 + 128];
  // b67 = fm_w1 @ g2e_b2 + fm_b1 (ea2 has no relu before fm_w1; fold valid)
  float sb = 0.f;
  for (int j = 0; j < 128; ++j) sb += fm_w1[o * 128 + j] * g2e_b2[j];
  b67[o] = sb + fm_b1[o];
}

// ---- pack weights [128][Kin] into bf16 B-fragment order; mi==5 computes
// W67 = fm_w1 @ g2e_w2 on the fly ----
struct PackArgs {
  const float* src[6];
  u16* dst[6];
  int Kin[6];
  int ksCum[7];
  const float* w6;  // g2e_w2
  const float* w7;  // fm_w1
};

__global__ void k_pack(PackArgs pa) {
  int bk = blockIdx.x;
  int mi = 0;
  while (bk >= pa.ksCum[mi + 1]) ++mi;
  int ks = bk - pa.ksCum[mi];
  const float* W = pa.src[mi];
  u16* D = pa.dst[mi] + ks * 4096;
  int Kin = pa.Kin[mi];
#pragma unroll
  for (int t = 0; t < 16; ++t) {
    int el = t * 256 + (int)threadIdx.x;
    int j = el & 7, ln = (el >> 3) & 63, ntile = el >> 9;
    int k = ks * 32 + ((ln >> 4) << 3) + j;
    int n = ntile * 16 + (ln & 15);
    float v;
    if (mi == 5) {
      float s = 0.f;
      for (int jj = 0; jj < 128; ++jj) s += pa.w7[n * 128 + jj] * pa.w6[jj * 128 + k];
      v = s;
    } else {
      v = (k < Kin) ? W[n * Kin + k] : 0.0f;
    }
    D[el] = f2bf(v);
  }
}

// ---- node encoder: 16 nodes per block ----
__global__ __launch_bounds__(256) void k_encode(const float* __restrict__ x,
                                                const float* __restrict__ node_type,
                                                const float* __restrict__ Mt,
                                                const float* __restrict__ C0,
                                                const float* __restrict__ Wnt,
                                                u16* __restrict__ h2) {
  __shared__ float xs[16][20], nts[16], mts[20 * 128];
  const int tid = threadIdx.x;
  const int n0 = blockIdx.x * 16;
  for (int i = tid; i < 320; i += 256) xs[i / 20][i % 20] = x[n0 * 20 + i];
  if (tid < 16) nts[tid] = node_type[n0 + tid];
  for (int i = tid; i < 2560; i += 256) mts[i] = Mt[i];
  __syncthreads();
  const int nl = tid >> 4;          // node in block
  const int c0 = (tid & 15) * 8;    // 8 consecutive channels
  float nt = nts[nl];
  union { u16 s[8]; uint4 u; } o;
#pragma unroll
  for (int i = 0; i < 8; ++i) {
    int ch = c0 + i;
    float acc = C0[ch] + Wnt[ch] * nt;
#pragma unroll
    for (int qq = 0; qq < 20; ++qq) acc += xs[nl][qq] * mts[qq * 128 + ch];
    o.s[i] = f2bf(acc);
  }
  *(uint4*)(h2 + (size_t)(n0 + nl) * HID + c0) = o.u;
}

// ---- gnn1: 2 LDS buffers -> 4 blocks/CU. ea1 = g1e(h2r,h2c,ea); h3 (blocks<313) ----
__global__ __launch_bounds__(256, 4) void k_gnn1(
    const int* __restrict__ eidx, const float* __restrict__ eattr,
    const u16* __restrict__ h2, const u16* __restrict__ pW1, const u16* __restrict__ pW2,
    const u16* __restrict__ pW3, const u16* __restrict__ pW4, const float* __restrict__ b1,
    const float* __restrict__ b2, const float* __restrict__ b3, const float* __restrict__ b4,
    u16* __restrict__ ea1, u16* __restrict__ h3) {
  __shared__ __align__(16) u16 B0[64 * STR], B1[64 * STR];
  const int tid = threadIdx.x, lane = tid & 63, wave = tid >> 6;
  const int e0 = blockIdx.x * 64;
  const int m = lane & 15, q = lane >> 4;
  const int aoff = m * STR + q * 8;
  const int* rowI = eidx;
  const int* colI = eidx + N_EDGES;

  stage_gather(rowI, colI, h2, B0, B1, e0, lane, wave);

  // eattr A-frags in registers (K-step 8 of GEMM1)
  bf16x8 ef[4];
#pragma unroll
  for (int mt = 0; mt < 4; ++mt) {
    union { u16 s[8]; uint4 u; bf16x8 v; } t;
    t.u = make_uint4(0u, 0u, 0u, 0u);
    if (q == 0) {
      float4 a = *(const float4*)(eattr + (size_t)(e0 + mt * 16 + m) * 4);
      t.s[0] = f2bf(a.x); t.s[1] = f2bf(a.y); t.s[2] = f2bf(a.z); t.s[3] = f2bf(a.w);
    }
    ef[mt] = t.v;
  }
  __syncthreads();  // S1

  f32x4 acc[4][2];
  zero_acc(acc);  // GEMM1: K=288: [B0 h2r | B1 h2c | eattr-regs]
  wgemm<9>(pW1, [&](int ks, int mt) -> bf16x8 {
    if (ks < 4) return ld8(B0 + aoff + mt * 16 * STR + ks * 32);
    if (ks < 8) return ld8(B1 + aoff + mt * 16 * STR + (ks - 4) * 32);
    return ef[mt];
  }, acc, lane, wave);
  __syncthreads();  // S2: all B0/B1 reads done
  epi_store<true>(B1, acc, b1, lane, wave);  // H -> B1 (h2c dead)
  __syncthreads();  // S3

  zero_acc(acc);  // GEMM2: ea1 = W2 x H
  wgemm<4>(pW2, [&](int ks, int mt) -> bf16x8 {
    return ld8(B1 + aoff + mt * 16 * STR + ks * 32);
  }, acc, lane, wave);
  epi_store<false>(B0, acc, b2, lane, wave);  // ea1 -> B0 (h2r dead since S2)
  __syncthreads();  // S4
  flush_buf(B0, ea1, e0, tid);

  if (e0 < N_NODES) {  // h3 only ever gathered at indices < N
    // re-gather h2row -> B1 (H dead after GEMM2; safe after S4). L2-hit, 313 blocks.
#pragma unroll
    for (int it = 0; it < 4; ++it) {
      int e = wave * 16 + it * 4 + q;  // 0..63
      int id = rowI[e0 + e];
      uint4 v = *(const uint4*)(h2 + (size_t)id * HID + m * 8);
      *(uint4*)(B1 + e * STR + m * 8) = v;
    }
    __syncthreads();  // S5

    zero_acc(acc);  // GEMM3: K=256: [B1 h2row | B0 ea1]
    wgemm<8>(pW3, [&](int ks, int mt) -> bf16x8 {
      if (ks < 4) return ld8(B1 + aoff + mt * 16 * STR + ks * 32);
      return ld8(B0 + aoff + mt * 16 * STR + (ks - 4) * 32);
    }, acc, lane, wave);
    __syncthreads();  // S6: all B0/B1 reads done (flush also long done)
    epi_store<true>(B1, acc, b3, lane, wave);  // H' -> B1
    __syncthreads();  // S7

    zero_acc(acc);  // GEMM4: h3 = W4 x H'
    wgemm<4>(pW4, [&](int ks, int mt) -> bf16x8 {
      return ld8(B1 + aoff + mt * 16 * STR + ks * 32);
    }, acc, lane, wave);
    epi_store<false>(B0, acc, b4, lane, wave);  // h3 -> B0 (ea1 dead since S6)
    __syncthreads();  // S8
    flush_buf(B0, h3, e0, tid);
  }
}

// ---- gnn2 (folded W67) + BN stats via atomics: 2 LDS buffers -> 4 blocks/CU ----
__global__ __launch_bounds__(256, 4) void k_gnn2(
    const int* __restrict__ eidx, const u16* __restrict__ h3, u16* ea1z,
    const u16* __restrict__ pW5, const u16* __restrict__ pW67,
    const float* __restrict__ b5, const float* __restrict__ b67,
    float* __restrict__ bnacc) {
  __shared__ __align__(16) u16 B0[64 * STR], B1[64 * STR];
  const int tid = threadIdx.x, lane = tid & 63, wave = tid >> 6;
  const int e0 = blockIdx.x * 64;
  const int m = lane & 15, q = lane >> 4;
  const int aoff = m * STR + q * 8;
  const int* rowI = eidx;
  const int* colI = eidx + N_EDGES;

  stage_gather(rowI, colI, h3, B0, B1, e0, lane, wave);
  __syncthreads();  // S1

  f32x4 acc[4][2];
  zero_acc(acc);  // GEMM1a: ks 0..7 of K=384: [B0 h3r | B1 h3c]
  wgemm<8>(pW5, [&](int ks, int mt) -> bf16x8 {
    if (ks < 4) return ld8(B0 + aoff + mt * 16 * STR + ks * 32);
    return ld8(B1 + aoff + mt * 16 * STR + (ks - 4) * 32);
  }, acc, lane, wave);
  __syncthreads();  // S2: all B0/B1 reads done

  // stage ea1 (own rows, coalesced) -> B0 (h3r dead)
#pragma unroll
  for (int it = 0; it < 4; ++it) {
    int cid = tid + it * 256, e = cid >> 4, p = cid & 15;
    uint4 v = *(const uint4*)(ea1z + (size_t)(e0 + e) * HID + p * 8);
    *(uint4*)(B0 + e * STR + p * 8) = v;
  }
  __syncthreads();  // S3

  // GEMM1b: ks 8..11 (ea1 part), accumulate into same acc
  wgemm<4>(pW5 + 8 * 4096, [&](int ks, int mt) -> bf16x8 {
    return ld8(B0 + aoff + mt * 16 * STR + ks * 32);
  }, acc, lane, wave);
  epi_store<true>(B1, acc, b5, lane, wave);  // H -> B1 (h3c dead since S2)
  __syncthreads();  // S4

  zero_acc(acc);  // GEMM2': z = (fm_w1 @ g2e_w2) @ H + b67
  wgemm<4>(pW67, [&](int ks, int mt) -> bf16x8 {
    return ld8(B1 + aoff + mt * 16 * STR + ks * 32);
  }, acc, lane, wave);

  // z epilogue -> B0 + per-channel BN partials (wave covers ch wave*32..+31)
  {
    const int c = lane & 15;
    const float bb0 = b67[wave * 32 + c], bb1 = b67[wave * 32 + 16 + c];
    float s0 = 0.f, q0 = 0.f, s1 = 0.f, q1 = 0.f;
#pragma unroll
    for (int mt = 0; mt < 4; ++mt)
#pragma unroll
      for (int r = 0; r < 4; ++r) {
        float v0 = acc[mt][0][r] + bb0;
        float v1 = acc[mt][1][r] + bb1;
        s0 += v0; q0 += v0 * v0;
        s1 += v1; q1 += v1 * v1;
        int row = mt * 16 + q * 4 + r;
        B0[row * STR + wave * 32 + c] = f2bf(v0);
        B0[row * STR + wave * 32 + 16 + c] = f2bf(v1);
      }
    s0 += __shfl_xor(s0, 16); s0 += __shfl_xor(s0, 32);
    q0 += __shfl_xor(q0, 16); q0 += __shfl_xor(q0, 32);
    s1 += __shfl_xor(s1, 16); s1 += __shfl_xor(s1, 32);
    q1 += __shfl_xor(q1, 16); q1 += __shfl_xor(q1, 32);
    if (lane < 16) {
      atomicAdd(&bnacc[wave * 32 + lane], s0);
      atomicAdd(&bnacc[wave * 32 + 16 + lane], s1);
      atomicAdd(&bnacc[128 + wave * 32 + lane], q0);
      atomicAdd(&bnacc[128 + wave * 32 + 16 + lane], q1);
    }
  }
  __syncthreads();  // S5
  flush_buf(B0, ea1z, e0, tid);  // z overwrites own ea1 rows (already consumed)
}

// ---- head: one edge per thread; BN finalize recomputed per block (cheap) ----
__global__ __launch_bounds__(256) void k_head(const u16* __restrict__ z,
                                              const float* __restrict__ bnacc,
                                              const float* __restrict__ bn_g,
                                              const float* __restrict__ bn_b,
                                              const float* __restrict__ w2,
                                              const float* __restrict__ b2,
                                              float* __restrict__ out) {
  __shared__ float sh_s[128], sh_h[128], sh_w0[128], sh_w1[128], sh_w2[128];
  const int tid = threadIdx.x;
  if (tid < 128) {
    const float inv = 1.0f / (float)N_EDGES;
    float mu = bnacc[tid] * inv;
    float var = bnacc[128 + tid] * inv - mu * mu;
    float sc = bn_g[tid] * rsqrtf(var + 1e-5f);
    sh_s[tid] = sc;
    sh_h[tid] = bn_b[tid] - mu * sc;
    sh_w0[tid] = w2[tid];
    sh_w1[tid] = w2[128 + tid];
    sh_w2[tid] = w2[256 + tid];
  }
  __syncthreads();
  const int e = blockIdx.x * 256 + tid;
  if (e >= N_EDGES) return;
  float a0 = b2[0], a1 = b2[1], a2 = b2[2];
  const u16* zr = z + (size_t)e * HID;
#pragma unroll
  for (int p = 0; p < 16; ++p) {
    uint4 v = *(const uint4*)(zr + p * 8);
    unsigned wv[4] = {v.x, v.y, v.z, v.w};
#pragma unroll
    for (int k = 0; k < 4; ++k) {
      int ch = p * 8 + k * 2;
      float lo = bf2f(wv[k] & 0xffffu), hi = bf2f(wv[k] >> 16);
      float r0 = fmaxf(fmaf(lo, sh_s[ch], sh_h[ch]), 0.f);
      float r1 = fmaxf(fmaf(hi, sh_s[ch + 1], sh_h[ch + 1]), 0.f);
      a0 += r0 * sh_w0[ch] + r1 * sh_w0[ch + 1];
      a1 += r0 * sh_w1[ch] + r1 * sh_w1[ch + 1];
      a2 += r0 * sh_w2[ch] + r1 * sh_w2[ch + 1];
    }
  }
  out[e * 3 + 0] = a0;
  out[e * 3 + 1] = a1;
  out[e * 3 + 2] = a2;
}

extern "C" void kernel_launch(void* const* d_in, const int* in_sizes, int n_in,
                              void* d_out, int out_size, void* d_ws, size_t ws_size,
                              hipStream_t stream) {
  const float* x         = (const float*)d_in[0];
  const int* eidx        = (const int*)d_in[1];
  const float* eattr     = (const float*)d_in[2];
  const float* node_type = (const float*)d_in[4];
  const float* emb       = (const float*)d_in[5];
  const float* conv_w    = (const float*)d_in[6];
  const float* conv_b    = (const float*)d_in[7];
  const float* fuse_w    = (const float*)d_in[8];
  const float* fuse_b    = (const float*)d_in[9];
  const float* g1e_w1    = (const float*)d_in[10];
  const float* g1e_b1    = (const float*)d_in[11];
  const float* g1e_w2    = (const float*)d_in[12];
  const float* g1e_b2    = (const float*)d_in[13];
  const float* g1n_w1    = (const float*)d_in[14];
  const float* g1n_b1    = (const float*)d_in[15];
  const float* g1n_w2    = (const float*)d_in[16];
  const float* g1n_b2    = (const float*)d_in[17];
  const float* g2e_w1    = (const float*)d_in[18];
  const float* g2e_b1    = (const float*)d_in[19];
  const float* g2e_w2    = (const float*)d_in[20];
  const float* g2e_b2    = (const float*)d_in[21];
  // d_in[22..25] = g2n_* : dead code in the reference (output unused)
  const float* fm_w1     = (const float*)d_in[26];
  const float* fm_b1     = (const float*)d_in[27];
  const float* bn_g      = (const float*)d_in[28];
  const float* bn_b      = (const float*)d_in[29];
  const float* fm_w2     = (const float*)d_in[30];
  const float* fm_b2     = (const float*)d_in[31];
  float* out = (float*)d_out;

  char* ws = (char*)d_ws;
  size_t off = 0;
  auto take = [&](size_t bytes) {
    void* p = ws + off;
    off = (off + bytes + 255) & ~(size_t)255;
    return p;
  };
  u16* h2   = (u16*)take((size_t)N_NODES * HID * 2);
  u16* h3   = (u16*)take((size_t)20032 * HID * 2);  // only rows < N ever gathered
  u16* ea1z = (u16*)take((size_t)N_EDGES * HID * 2);
  float* Mt    = (float*)take(20 * 128 * 4);
  float* C0    = (float*)take(128 * 4);
  float* Wnt   = (float*)take(128 * 4);
  float* bnacc = (float*)take(256 * 4);
  float* b67   = (float*)take(128 * 4);
  u16* pW1  = (u16*)take(9 * 4096 * 2);
  u16* pW2  = (u16*)take(4 * 4096 * 2);
  u16* pW3  = (u16*)take(8 * 4096 * 2);
  u16* pW4  = (u16*)take(4 * 4096 * 2);
  u16* pW5  = (u16*)take(12 * 4096 * 2);
  u16* pW67 = (u16*)take(4 * 4096 * 2);

  hipMemsetAsync(bnacc, 0, 256 * 4, stream);
  k_fold<<<1, 128, 0, stream>>>(emb, conv_w, conv_b, fuse_w, fuse_b,
                                fm_w1, g2e_b2, fm_b1, Mt, C0, Wnt, b67);

  PackArgs pa;
  const float* srcs[6] = {g1e_w1, g1e_w2, g1n_w1, g1n_w2, g2e_w1, nullptr};
  u16* dsts[6] = {pW1, pW2, pW3, pW4, pW5, pW67};
  int kins[6] = {260, 128, 256, 128, 384, 128};
  int kst[6] = {9, 4, 8, 4, 12, 4};
  int cum = 0;
  for (int i = 0; i < 6; ++i) {
    pa.src[i] = srcs[i]; pa.dst[i] = dsts[i]; pa.Kin[i] = kins[i];
    pa.ksCum[i] = cum; cum += kst[i];
  }
  pa.ksCum[6] = cum;  // 41
  pa.w6 = g2e_w2;
  pa.w7 = fm_w1;
  k_pack<<<41, 256, 0, stream>>>(pa);

  k_encode<<<N_NODES / 16, 256, 0, stream>>>(x, node_type, Mt, C0, Wnt, h2);
  k_gnn1<<<NBLK, 256, 0, stream>>>(eidx, eattr, h2, pW1, pW2, pW3, pW4,
                                   g1e_b1, g1e_b2, g1n_b1, g1n_b2, ea1z, h3);
  k_gnn2<<<NBLK, 256, 0, stream>>>(eidx, h3, ea1z, pW5, pW67,
                                   g2e_b1, b67, bnacc);
  k_head<<<(N_EDGES + 255) / 256, 256, 0, stream>>>(ea1z, bnacc, bn_g, bn_b,
                                                    fm_w2, fm_b2, out);
}

// Round 9
// 314.945 us; speedup vs baseline: 1.1119x; 1.1119x over previous
//
#include <hip/hip_runtime.h>

#define N_NODES 20000
#define N_EDGES 200000
#define HID 128
#define STR 136   // LDS row stride in u16: 272B rows -> every b128 access 16B-aligned
#define NBLK 3125 // 64-edge tiles

typedef unsigned short u16;
using bf16x8 = __attribute__((ext_vector_type(8))) __bf16;
using f32x4  = __attribute__((ext_vector_type(4))) float;

__device__ __forceinline__ u16 f2bf(float f) {
  union { float f; unsigned u; } v; v.f = f;
  unsigned u = v.u;
  return (u16)((u + 0x7FFFu + ((u >> 16) & 1u)) >> 16);
}
__device__ __forceinline__ float bf2f(unsigned s) {
  union { unsigned u; float f; } v; v.u = s << 16;
  return v.f;
}
__device__ __forceinline__ bf16x8 ld8(const u16* p) { return *(const bf16x8*)p; }

__device__ __forceinline__ void zero_acc(f32x4 acc[4][2]) {
#pragma unroll
  for (int i = 0; i < 4; ++i) {
    acc[i][0] = (f32x4){0.f, 0.f, 0.f, 0.f};
    acc[i][1] = (f32x4){0.f, 0.f, 0.f, 0.f};
  }
}

// GEMM: D[64 edges][128 ch] += A(edges, via afrag)[64][K] * B(packed W)[K][128].
// Wave w owns n-tiles {2w,2w+1}. Depth-2 explicit B prefetch ring hides L2 latency.
template <int KSTEPS, typename AF>
__device__ __forceinline__ void wgemm(const u16* __restrict__ PW, AF afrag,
                                      f32x4 acc[4][2], int lane, int wave) {
  const u16* pb = PW + (wave * 2 * 64 + lane) * 8;
  bf16x8 b0[2], b1[2];
  b0[0] = ld8(pb);
  b1[0] = ld8(pb + 512);
#pragma unroll
  for (int ks = 0; ks < KSTEPS; ++ks) {
    const int cur = ks & 1, nxt = cur ^ 1;
    if (ks + 1 < KSTEPS) {
      b0[nxt] = ld8(pb + (ks + 1) * 4096);
      b1[nxt] = ld8(pb + (ks + 1) * 4096 + 512);
    }
#pragma unroll
    for (int mt = 0; mt < 4; ++mt) {
      bf16x8 a = afrag(ks, mt);
      acc[mt][0] = __builtin_amdgcn_mfma_f32_16x16x32_bf16(a, b0[cur], acc[mt][0], 0, 0, 0);
      acc[mt][1] = __builtin_amdgcn_mfma_f32_16x16x32_bf16(a, b1[cur], acc[mt][1], 0, 0, 0);
    }
  }
}

// C/D: row(edge) = mt*16 + (lane>>4)*4 + r, col(ch) = wave*32 + nt*16 + (lane&15).
template <bool RELU>
__device__ __forceinline__ void epi_store(u16* buf, const f32x4 acc[4][2],
                                          const float* __restrict__ bias,
                                          int lane, int wave) {
  const int c = lane & 15, q = lane >> 4;
  const float bb0 = bias[wave * 32 + c], bb1 = bias[wave * 32 + 16 + c];
#pragma unroll
  for (int mt = 0; mt < 4; ++mt)
#pragma unroll
    for (int nt = 0; nt < 2; ++nt) {
      const float bb = nt ? bb1 : bb0;
      const int col = wave * 32 + nt * 16 + c;
#pragma unroll
      for (int r = 0; r < 4; ++r) {
        float v = acc[mt][nt][r] + bb;
        if (RELU) v = fmaxf(v, 0.f);
        buf[(mt * 16 + q * 4 + r) * STR + col] = f2bf(v);
      }
    }
}

__device__ __forceinline__ void flush_buf(const u16* buf, u16* __restrict__ gout,
                                          int e0, int tid) {
#pragma unroll
  for (int it = 0; it < 4; ++it) {
    int cid = tid + it * 256, e = cid >> 4, p = cid & 15;
    uint4 v = *(const uint4*)(buf + e * STR + p * 8);
    *(uint4*)(gout + (size_t)(e0 + e) * HID + p * 8) = v;
  }
}

// TA-friendly gather: 16 lanes cooperate per row (4 rows x 16 pieces per instr
// -> 8 distinct cache lines, not 64). Covers 128 rows (64 row-gathers -> B0,
// 64 col-gathers -> B1).
__device__ __forceinline__ void stage_gather(const int* __restrict__ rowI,
                                             const int* __restrict__ colI,
                                             const u16* __restrict__ htab,
                                             u16* B0, u16* B1,
                                             int e0, int lane, int wave) {
  const int r = lane >> 4, p = lane & 15;
#pragma unroll
  for (int it = 0; it < 8; ++it) {
    int j = wave * 32 + it * 4 + r;  // 0..127
    int e = j & 63;
    int id = (j < 64) ? rowI[e0 + e] : colI[e0 + e];
    uint4 v = *(const uint4*)(htab + (size_t)id * HID + p * 8);
    *(uint4*)(((j < 64) ? B0 : B1) + e * STR + p * 8) = v;
  }
}

// ---- fold encoder (conv1d+mean+fuse) into M[128x20], C0, Wnt; also b67 ----
__global__ void k_fold(const float* __restrict__ emb, const float* __restrict__ conv_w,
                       const float* __restrict__ conv_b, const float* __restrict__ fuse_w,
                       const float* __restrict__ fuse_b,
                       const float* __restrict__ fm_w1, const float* __restrict__ g2e_b2,
                       const float* __restrict__ fm_b1,
                       float* __restrict__ Mt, float* __restrict__ C0,
                       float* __restrict__ Wnt, float* __restrict__ b67) {
  __shared__ float Ash[128][21];
  int o = threadIdx.x;  // 128 threads
  {
    float b0 = conv_b[o];
#pragma unroll
    for (int p = 0; p < 5; ++p) {
#pragma unroll
      for (int i = 0; i < 8; ++i) {
        float s = 0.f;
#pragma unroll
        for (int k = 0; k < 3; ++k) {
          int t = p + 1 - k;
          if (t >= 0 && t < 5) s += conv_w[(o * 8 + i) * 3 + k];
        }
        s *= 0.2f;
        if (i < 4) Ash[o][p * 4 + i] = s;
        else b0 += emb[p * 4 + (i - 4)] * s;
      }
    }
    Ash[o][20] = b0;
  }
  __syncthreads();
  float m[20];
#pragma unroll
  for (int qq = 0; qq < 20; ++qq) m[qq] = 0.f;
  float c0 = fuse_b[o];
  for (int j = 0; j < 128; ++j) {
    float w = fuse_w[o * 129 + j];
#pragma unroll
    for (int qq = 0; qq < 20; ++qq) m[qq] += w * Ash[j][qq];
    c0 += w * Ash[j][20];
  }
#pragma unroll
  for (int qq = 0; qq < 20; ++qq) Mt[qq * 128 + o] = m[qq];
  C0[o] = c0;
  Wnt[o] = fuse_w[o * 129 + 128];
  // b67 = fm_w1 @ g2e_b2 + fm_b1 (ea2 has no relu before fm_w1; fold valid)
  float sb = 0.f;
  for (int j = 0; j < 128; ++j) sb += fm_w1[o * 128 + j] * g2e_b2[j];
  b67[o] = sb + fm_b1[o];
}

// ---- pack weights [128][Kin] into bf16 B-fragment order; mi==5 computes
// W67 = fm_w1 @ g2e_w2 on the fly ----
struct PackArgs {
  const float* src[6];
  u16* dst[6];
  int Kin[6];
  int ksCum[7];
  const float* w6;  // g2e_w2
  const float* w7;  // fm_w1
};

__global__ void k_pack(PackArgs pa) {
  int bk = blockIdx.x;
  int mi = 0;
  while (bk >= pa.ksCum[mi + 1]) ++mi;
  int ks = bk - pa.ksCum[mi];
  const float* W = pa.src[mi];
  u16* D = pa.dst[mi] + ks * 4096;
  int Kin = pa.Kin[mi];
#pragma unroll
  for (int t = 0; t < 16; ++t) {
    int el = t * 256 + (int)threadIdx.x;
    int j = el & 7, ln = (el >> 3) & 63, ntile = el >> 9;
    int k = ks * 32 + ((ln >> 4) << 3) + j;
    int n = ntile * 16 + (ln & 15);
    float v;
    if (mi == 5) {
      float s = 0.f;
      for (int jj = 0; jj < 128; ++jj) s += pa.w7[n * 128 + jj] * pa.w6[jj * 128 + k];
      v = s;
    } else {
      v = (k < Kin) ? W[n * Kin + k] : 0.0f;
    }
    D[el] = f2bf(v);
  }
}

// ---- node encoder: 16 nodes per block ----
__global__ __launch_bounds__(256) void k_encode(const float* __restrict__ x,
                                                const float* __restrict__ node_type,
                                                const float* __restrict__ Mt,
                                                const float* __restrict__ C0,
                                                const float* __restrict__ Wnt,
                                                u16* __restrict__ h2) {
  __shared__ float xs[16][20], nts[16], mts[20 * 128];
  const int tid = threadIdx.x;
  const int n0 = blockIdx.x * 16;
  for (int i = tid; i < 320; i += 256) xs[i / 20][i % 20] = x[n0 * 20 + i];
  if (tid < 16) nts[tid] = node_type[n0 + tid];
  for (int i = tid; i < 2560; i += 256) mts[i] = Mt[i];
  __syncthreads();
  const int nl = tid >> 4;          // node in block
  const int c0 = (tid & 15) * 8;    // 8 consecutive channels
  float nt = nts[nl];
  union { u16 s[8]; uint4 u; } o;
#pragma unroll
  for (int i = 0; i < 8; ++i) {
    int ch = c0 + i;
    float acc = C0[ch] + Wnt[ch] * nt;
#pragma unroll
    for (int qq = 0; qq < 20; ++qq) acc += xs[nl][qq] * mts[qq * 128 + ch];
    o.s[i] = f2bf(acc);
  }
  *(uint4*)(h2 + (size_t)(n0 + nl) * HID + c0) = o.u;
}

// ---- gnn1: 2 LDS buffers -> 4 blocks/CU. ea1 = g1e(h2r,h2c,ea); h3 (blocks<313) ----
__global__ __launch_bounds__(256, 4) void k_gnn1(
    const int* __restrict__ eidx, const float* __restrict__ eattr,
    const u16* __restrict__ h2, const u16* __restrict__ pW1, const u16* __restrict__ pW2,
    const u16* __restrict__ pW3, const u16* __restrict__ pW4, const float* __restrict__ b1,
    const float* __restrict__ b2, const float* __restrict__ b3, const float* __restrict__ b4,
    u16* __restrict__ ea1, u16* __restrict__ h3) {
  __shared__ __align__(16) u16 B0[64 * STR], B1[64 * STR];
  const int tid = threadIdx.x, lane = tid & 63, wave = tid >> 6;
  const int e0 = blockIdx.x * 64;
  const int m = lane & 15, q = lane >> 4;
  const int aoff = m * STR + q * 8;
  const int* rowI = eidx;
  const int* colI = eidx + N_EDGES;

  stage_gather(rowI, colI, h2, B0, B1, e0, lane, wave);

  // eattr A-frags in registers (K-step 8 of GEMM1)
  bf16x8 ef[4];
#pragma unroll
  for (int mt = 0; mt < 4; ++mt) {
    union { u16 s[8]; uint4 u; bf16x8 v; } t;
    t.u = make_uint4(0u, 0u, 0u, 0u);
    if (q == 0) {
      float4 a = *(const float4*)(eattr + (size_t)(e0 + mt * 16 + m) * 4);
      t.s[0] = f2bf(a.x); t.s[1] = f2bf(a.y); t.s[2] = f2bf(a.z); t.s[3] = f2bf(a.w);
    }
    ef[mt] = t.v;
  }
  __syncthreads();  // S1

  f32x4 acc[4][2];
  zero_acc(acc);  // GEMM1: K=288: [B0 h2r | B1 h2c | eattr-regs]
  wgemm<9>(pW1, [&](int ks, int mt) -> bf16x8 {
    if (ks < 4) return ld8(B0 + aoff + mt * 16 * STR + ks * 32);
    if (ks < 8) return ld8(B1 + aoff + mt * 16 * STR + (ks - 4) * 32);
    return ef[mt];
  }, acc, lane, wave);
  __syncthreads();  // S2: all B0/B1 reads done
  epi_store<true>(B1, acc, b1, lane, wave);  // H -> B1 (h2c dead)
  __syncthreads();  // S3

  zero_acc(acc);  // GEMM2: ea1 = W2 x H
  wgemm<4>(pW2, [&](int ks, int mt) -> bf16x8 {
    return ld8(B1 + aoff + mt * 16 * STR + ks * 32);
  }, acc, lane, wave);
  epi_store<false>(B0, acc, b2, lane, wave);  // ea1 -> B0 (h2r dead since S2)
  __syncthreads();  // S4
  flush_buf(B0, ea1, e0, tid);

  if (e0 < N_NODES) {  // h3 only ever gathered at indices < N
    // re-gather h2row -> B1 (H dead after GEMM2; safe after S4). L2-hit, 313 blocks.
#pragma unroll
    for (int it = 0; it < 4; ++it) {
      int e = wave * 16 + it * 4 + q;  // 0..63
      int id = rowI[e0 + e];
      uint4 v = *(const uint4*)(h2 + (size_t)id * HID + m * 8);
      *(uint4*)(B1 + e * STR + m * 8) = v;
    }
    __syncthreads();  // S5

    zero_acc(acc);  // GEMM3: K=256: [B1 h2row | B0 ea1]
    wgemm<8>(pW3, [&](int ks, int mt) -> bf16x8 {
      if (ks < 4) return ld8(B1 + aoff + mt * 16 * STR + ks * 32);
      return ld8(B0 + aoff + mt * 16 * STR + (ks - 4) * 32);
    }, acc, lane, wave);
    __syncthreads();  // S6: all B0/B1 reads done (flush also long done)
    epi_store<true>(B1, acc, b3, lane, wave);  // H' -> B1
    __syncthreads();  // S7

    zero_acc(acc);  // GEMM4: h3 = W4 x H'
    wgemm<4>(pW4, [&](int ks, int mt) -> bf16x8 {
      return ld8(B1 + aoff + mt * 16 * STR + ks * 32);
    }, acc, lane, wave);
    epi_store<false>(B0, acc, b4, lane, wave);  // h3 -> B0 (ea1 dead since S6)
    __syncthreads();  // S8
    flush_buf(B0, h3, e0, tid);
  }
}

// ---- gnn2 (folded W67) + BN stats via per-block partials (NOT atomics: 200k
// same-line atomics serialized L2 and doubled this kernel in r8) ----
__global__ __launch_bounds__(256, 4) void k_gnn2(
    const int* __restrict__ eidx, const u16* __restrict__ h3, u16* ea1z,
    const u16* __restrict__ pW5, const u16* __restrict__ pW67,
    const float* __restrict__ b5, const float* __restrict__ b67,
    float* __restrict__ partials) {
  __shared__ __align__(16) u16 B0[64 * STR], B1[64 * STR];
  const int tid = threadIdx.x, lane = tid & 63, wave = tid >> 6;
  const int e0 = blockIdx.x * 64;
  const int m = lane & 15, q = lane >> 4;
  const int aoff = m * STR + q * 8;
  const int* rowI = eidx;
  const int* colI = eidx + N_EDGES;

  stage_gather(rowI, colI, h3, B0, B1, e0, lane, wave);
  __syncthreads();  // S1

  f32x4 acc[4][2];
  zero_acc(acc);  // GEMM1a: ks 0..7 of K=384: [B0 h3r | B1 h3c]
  wgemm<8>(pW5, [&](int ks, int mt) -> bf16x8 {
    if (ks < 4) return ld8(B0 + aoff + mt * 16 * STR + ks * 32);
    return ld8(B1 + aoff + mt * 16 * STR + (ks - 4) * 32);
  }, acc, lane, wave);
  __syncthreads();  // S2: all B0/B1 reads done

  // stage ea1 (own rows, coalesced) -> B0 (h3r dead)
#pragma unroll
  for (int it = 0; it < 4; ++it) {
    int cid = tid + it * 256, e = cid >> 4, p = cid & 15;
    uint4 v = *(const uint4*)(ea1z + (size_t)(e0 + e) * HID + p * 8);
    *(uint4*)(B0 + e * STR + p * 8) = v;
  }
  __syncthreads();  // S3

  // GEMM1b: ks 8..11 (ea1 part), accumulate into same acc
  wgemm<4>(pW5 + 8 * 4096, [&](int ks, int mt) -> bf16x8 {
    return ld8(B0 + aoff + mt * 16 * STR + ks * 32);
  }, acc, lane, wave);
  epi_store<true>(B1, acc, b5, lane, wave);  // H -> B1 (h3c dead since S2)
  __syncthreads();  // S4

  zero_acc(acc);  // GEMM2': z = (fm_w1 @ g2e_w2) @ H + b67
  wgemm<4>(pW67, [&](int ks, int mt) -> bf16x8 {
    return ld8(B1 + aoff + mt * 16 * STR + ks * 32);
  }, acc, lane, wave);

  // z epilogue -> B0 + per-channel BN partials (wave covers ch wave*32..+31)
  {
    const int c = lane & 15;
    const float bb0 = b67[wave * 32 + c], bb1 = b67[wave * 32 + 16 + c];
    float s0 = 0.f, q0 = 0.f, s1 = 0.f, q1 = 0.f;
#pragma unroll
    for (int mt = 0; mt < 4; ++mt)
#pragma unroll
      for (int r = 0; r < 4; ++r) {
        float v0 = acc[mt][0][r] + bb0;
        float v1 = acc[mt][1][r] + bb1;
        s0 += v0; q0 += v0 * v0;
        s1 += v1; q1 += v1 * v1;
        int row = mt * 16 + q * 4 + r;
        B0[row * STR + wave * 32 + c] = f2bf(v0);
        B0[row * STR + wave * 32 + 16 + c] = f2bf(v1);
      }
    s0 += __shfl_xor(s0, 16); s0 += __shfl_xor(s0, 32);
    q0 += __shfl_xor(q0, 16); q0 += __shfl_xor(q0, 32);
    s1 += __shfl_xor(s1, 16); s1 += __shfl_xor(s1, 32);
    q1 += __shfl_xor(q1, 16); q1 += __shfl_xor(q1, 32);
    if (lane < 16) {
      int base = (int)blockIdx.x * 256;
      partials[base + wave * 32 + lane] = s0;
      partials[base + wave * 32 + 16 + lane] = s1;
      partials[base + 128 + wave * 32 + lane] = q0;
      partials[base + 128 + wave * 32 + 16 + lane] = q1;
    }
  }
  __syncthreads();  // S5
  flush_buf(B0, ea1z, e0, tid);  // z overwrites own ea1 rows (already consumed)
}

__global__ void k_reduce(const float* __restrict__ partials, float* __restrict__ bnacc,
                         int nrows) {
  int t = threadIdx.x;  // 256
  float s = 0.f;
  for (int b = blockIdx.x; b < nrows; b += 64) s += partials[b * 256 + t];
  atomicAdd(&bnacc[t], s);
}

// ---- head: one edge per thread; BN finalize recomputed per block (cheap) ----
__global__ __launch_bounds__(256) void k_head(const u16* __restrict__ z,
                                              const float* __restrict__ bnacc,
                                              const float* __restrict__ bn_g,
                                              const float* __restrict__ bn_b,
                                              const float* __restrict__ w2,
                                              const float* __restrict__ b2,
                                              float* __restrict__ out) {
  __shared__ float sh_s[128], sh_h[128], sh_w0[128], sh_w1[128], sh_w2[128];
  const int tid = threadIdx.x;
  if (tid < 128) {
    const float inv = 1.0f / (float)N_EDGES;
    float mu = bnacc[tid] * inv;
    float var = bnacc[128 + tid] * inv - mu * mu;
    float sc = bn_g[tid] * rsqrtf(var + 1e-5f);
    sh_s[tid] = sc;
    sh_h[tid] = bn_b[tid] - mu * sc;
    sh_w0[tid] = w2[tid];
    sh_w1[tid] = w2[128 + tid];
    sh_w2[tid] = w2[256 + tid];
  }
  __syncthreads();
  const int e = blockIdx.x * 256 + tid;
  if (e >= N_EDGES) return;
  float a0 = b2[0], a1 = b2[1], a2 = b2[2];
  const u16* zr = z + (size_t)e * HID;
#pragma unroll
  for (int p = 0; p < 16; ++p) {
    uint4 v = *(const uint4*)(zr + p * 8);
    unsigned wv[4] = {v.x, v.y, v.z, v.w};
#pragma unroll
    for (int k = 0; k < 4; ++k) {
      int ch = p * 8 + k * 2;
      float lo = bf2f(wv[k] & 0xffffu), hi = bf2f(wv[k] >> 16);
      float r0 = fmaxf(fmaf(lo, sh_s[ch], sh_h[ch]), 0.f);
      float r1 = fmaxf(fmaf(hi, sh_s[ch + 1], sh_h[ch + 1]), 0.f);
      a0 += r0 * sh_w0[ch] + r1 * sh_w0[ch + 1];
      a1 += r0 * sh_w1[ch] + r1 * sh_w1[ch + 1];
      a2 += r0 * sh_w2[ch] + r1 * sh_w2[ch + 1];
    }
  }
  out[e * 3 + 0] = a0;
  out[e * 3 + 1] = a1;
  out[e * 3 + 2] = a2;
}

extern "C" void kernel_launch(void* const* d_in, const int* in_sizes, int n_in,
                              void* d_out, int out_size, void* d_ws, size_t ws_size,
                              hipStream_t stream) {
  const float* x         = (const float*)d_in[0];
  const int* eidx        = (const int*)d_in[1];
  const float* eattr     = (const float*)d_in[2];
  const float* node_type = (const float*)d_in[4];
  const float* emb       = (const float*)d_in[5];
  const float* conv_w    = (const float*)d_in[6];
  const float* conv_b    = (const float*)d_in[7];
  const float* fuse_w    = (const float*)d_in[8];
  const float* fuse_b    = (const float*)d_in[9];
  const float* g1e_w1    = (const float*)d_in[10];
  const float* g1e_b1    = (const float*)d_in[11];
  const float* g1e_w2    = (const float*)d_in[12];
  const float* g1e_b2    = (const float*)d_in[13];
  const float* g1n_w1    = (const float*)d_in[14];
  const float* g1n_b1    = (const float*)d_in[15];
  const float* g1n_w2    = (const float*)d_in[16];
  const float* g1n_b2    = (const float*)d_in[17];
  const float* g2e_w1    = (const float*)d_in[18];
  const float* g2e_b1    = (const float*)d_in[19];
  const float* g2e_w2    = (const float*)d_in[20];
  const float* g2e_b2    = (const float*)d_in[21];
  // d_in[22..25] = g2n_* : dead code in the reference (output unused)
  const float* fm_w1     = (const float*)d_in[26];
  const float* fm_b1     = (const float*)d_in[27];
  const float* bn_g      = (const float*)d_in[28];
  const float* bn_b      = (const float*)d_in[29];
  const float* fm_w2     = (const float*)d_in[30];
  const float* fm_b2     = (const float*)d_in[31];
  float* out = (float*)d_out;

  char* ws = (char*)d_ws;
  size_t off = 0;
  auto take = [&](size_t bytes) {
    void* p = ws + off;
    off = (off + bytes + 255) & ~(size_t)255;
    return p;
  };
  u16* h2   = (u16*)take((size_t)N_NODES * HID * 2);
  u16* h3   = (u16*)take((size_t)20032 * HID * 2);  // only rows < N ever gathered
  u16* ea1z = (u16*)take((size_t)N_EDGES * HID * 2);
  float* Mt    = (float*)take(20 * 128 * 4);
  float* C0    = (float*)take(128 * 4);
  float* Wnt   = (float*)take(128 * 4);
  float* bnacc = (float*)take(256 * 4);
  float* b67   = (float*)take(128 * 4);
  float* partials = (float*)take((size_t)NBLK * 256 * 4);
  u16* pW1  = (u16*)take(9 * 4096 * 2);
  u16* pW2  = (u16*)take(4 * 4096 * 2);
  u16* pW3  = (u16*)take(8 * 4096 * 2);
  u16* pW4  = (u16*)take(4 * 4096 * 2);
  u16* pW5  = (u16*)take(12 * 4096 * 2);
  u16* pW67 = (u16*)take(4 * 4096 * 2);

  hipMemsetAsync(bnacc, 0, 256 * 4, stream);
  k_fold<<<1, 128, 0, stream>>>(emb, conv_w, conv_b, fuse_w, fuse_b,
                                fm_w1, g2e_b2, fm_b1, Mt, C0, Wnt, b67);

  PackArgs pa;
  const float* srcs[6] = {g1e_w1, g1e_w2, g1n_w1, g1n_w2, g2e_w1, nullptr};
  u16* dsts[6] = {pW1, pW2, pW3, pW4, pW5, pW67};
  int kins[6] = {260, 128, 256, 128, 384, 128};
  int kst[6] = {9, 4, 8, 4, 12, 4};
  int cum = 0;
  for (int i = 0; i < 6; ++i) {
    pa.src[i] = srcs[i]; pa.dst[i] = dsts[i]; pa.Kin[i] = kins[i];
    pa.ksCum[i] = cum; cum += kst[i];
  }
  pa.ksCum[6] = cum;  // 41
  pa.w6 = g2e_w2;
  pa.w7 = fm_w1;
  k_pack<<<41, 256, 0, stream>>>(pa);

  k_encode<<<N_NODES / 16, 256, 0, stream>>>(x, node_type, Mt, C0, Wnt, h2);
  k_gnn1<<<NBLK, 256, 0, stream>>>(eidx, eattr, h2, pW1, pW2, pW3, pW4,
                                   g1e_b1, g1e_b2, g1n_b1, g1n_b2, ea1z, h3);
  k_gnn2<<<NBLK, 256, 0, stream>>>(eidx, h3, ea1z, pW5, pW67,
                                   g2e_b1, b67, partials);
  k_reduce<<<64, 256, 0, stream>>>(partials, bnacc, NBLK);
  k_head<<<(N_EDGES + 255) / 256, 256, 0, stream>>>(ea1z, bnacc, bn_g, bn_b,
                                                    fm_w2, fm_b2, out);
}

// Round 10
// 277.302 us; speedup vs baseline: 1.2629x; 1.1357x over previous
//
#include <hip/hip_runtime.h>

#define N_NODES 20000
#define N_EDGES 200000
#define HID 128
#define STR 136   // LDS row stride in u16: 272B rows -> every b128 access 16B-aligned
#define NBLK 3125 // 64-edge tiles

typedef unsigned short u16;
using bf16x8 = __attribute__((ext_vector_type(8))) __bf16;
using f32x4  = __attribute__((ext_vector_type(4))) float;

__device__ __forceinline__ u16 f2bf(float f) {
  union { float f; unsigned u; } v; v.f = f;
  unsigned u = v.u;
  return (u16)((u + 0x7FFFu + ((u >> 16) & 1u)) >> 16);
}
__device__ __forceinline__ float bf2f(unsigned s) {
  union { unsigned u; float f; } v; v.u = s << 16;
  return v.f;
}
__device__ __forceinline__ bf16x8 ld8(const u16* p) { return *(const bf16x8*)p; }

__device__ __forceinline__ void zero_acc(f32x4 acc[4][2]) {
#pragma unroll
  for (int i = 0; i < 4; ++i) {
    acc[i][0] = (f32x4){0.f, 0.f, 0.f, 0.f};
    acc[i][1] = (f32x4){0.f, 0.f, 0.f, 0.f};
  }
}

// GEMM: D[64 edges][128 ch] += A(edges, via afrag)[64][K] * B(packed W)[K][128].
// Wave w owns n-tiles {2w,2w+1}. Depth-2 explicit B prefetch ring hides L2 latency.
template <int KSTEPS, typename AF>
__device__ __forceinline__ void wgemm(const u16* __restrict__ PW, AF afrag,
                                      f32x4 acc[4][2], int lane, int wave) {
  const u16* pb = PW + (wave * 2 * 64 + lane) * 8;
  bf16x8 b0[2], b1[2];
  b0[0] = ld8(pb);
  b1[0] = ld8(pb + 512);
#pragma unroll
  for (int ks = 0; ks < KSTEPS; ++ks) {
    const int cur = ks & 1, nxt = cur ^ 1;
    if (ks + 1 < KSTEPS) {
      b0[nxt] = ld8(pb + (ks + 1) * 4096);
      b1[nxt] = ld8(pb + (ks + 1) * 4096 + 512);
    }
#pragma unroll
    for (int mt = 0; mt < 4; ++mt) {
      bf16x8 a = afrag(ks, mt);
      acc[mt][0] = __builtin_amdgcn_mfma_f32_16x16x32_bf16(a, b0[cur], acc[mt][0], 0, 0, 0);
      acc[mt][1] = __builtin_amdgcn_mfma_f32_16x16x32_bf16(a, b1[cur], acc[mt][1], 0, 0, 0);
    }
  }
}

// C/D: row(edge) = mt*16 + (lane>>4)*4 + r, col(ch) = wave*32 + nt*16 + (lane&15).
template <bool RELU>
__device__ __forceinline__ void epi_store(u16* buf, const f32x4 acc[4][2],
                                          const float* __restrict__ bias,
                                          int lane, int wave) {
  const int c = lane & 15, q = lane >> 4;
  const float bb0 = bias[wave * 32 + c], bb1 = bias[wave * 32 + 16 + c];
#pragma unroll
  for (int mt = 0; mt < 4; ++mt)
#pragma unroll
    for (int nt = 0; nt < 2; ++nt) {
      const float bb = nt ? bb1 : bb0;
      const int col = wave * 32 + nt * 16 + c;
#pragma unroll
      for (int r = 0; r < 4; ++r) {
        float v = acc[mt][nt][r] + bb;
        if (RELU) v = fmaxf(v, 0.f);
        buf[(mt * 16 + q * 4 + r) * STR + col] = f2bf(v);
      }
    }
}

__device__ __forceinline__ void flush_buf(const u16* buf, u16* __restrict__ gout,
                                          int e0, int tid) {
#pragma unroll
  for (int it = 0; it < 4; ++it) {
    int cid = tid + it * 256, e = cid >> 4, p = cid & 15;
    uint4 v = *(const uint4*)(buf + e * STR + p * 8);
    *(uint4*)(gout + (size_t)(e0 + e) * HID + p * 8) = v;
  }
}

// TA-friendly gather: 16 lanes cooperate per row (4 rows x 16 pieces per instr
// -> 8 distinct cache lines, not 64). Covers 128 rows (64 row-gathers -> B0,
// 64 col-gathers -> B1).
__device__ __forceinline__ void stage_gather(const int* __restrict__ rowI,
                                             const int* __restrict__ colI,
                                             const u16* __restrict__ htab,
                                             u16* B0, u16* B1,
                                             int e0, int lane, int wave) {
  const int r = lane >> 4, p = lane & 15;
#pragma unroll
  for (int it = 0; it < 8; ++it) {
    int j = wave * 32 + it * 4 + r;  // 0..127
    int e = j & 63;
    int id = (j < 64) ? rowI[e0 + e] : colI[e0 + e];
    uint4 v = *(const uint4*)(htab + (size_t)id * HID + p * 8);
    *(uint4*)(((j < 64) ? B0 : B1) + e * STR + p * 8) = v;
  }
}

// ---- fold encoder (conv1d+mean+fuse) into M[128x20], C0, Wnt; also b67 ----
__global__ void k_fold(const float* __restrict__ emb, const float* __restrict__ conv_w,
                       const float* __restrict__ conv_b, const float* __restrict__ fuse_w,
                       const float* __restrict__ fuse_b,
                       const float* __restrict__ fm_w1, const float* __restrict__ g2e_b2,
                       const float* __restrict__ fm_b1,
                       float* __restrict__ Mt, float* __restrict__ C0,
                       float* __restrict__ Wnt, float* __restrict__ b67) {
  __shared__ float Ash[128][21];
  int o = threadIdx.x;  // 128 threads
  {
    float b0 = conv_b[o];
#pragma unroll
    for (int p = 0; p < 5; ++p) {
#pragma unroll
      for (int i = 0; i < 8; ++i) {
        float s = 0.f;
#pragma unroll
        for (int k = 0; k < 3; ++k) {
          int t = p + 1 - k;
          if (t >= 0 && t < 5) s += conv_w[(o * 8 + i) * 3 + k];
        }
        s *= 0.2f;
        if (i < 4) Ash[o][p * 4 + i] = s;
        else b0 += emb[p * 4 + (i - 4)] * s;
      }
    }
    Ash[o][20] = b0;
  }
  __syncthreads();
  float m[20];
#pragma unroll
  for (int qq = 0; qq < 20; ++qq) m[qq] = 0.f;
  float c0 = fuse_b[o];
  for (int j = 0; j < 128; ++j) {
    float w = fuse_w[o * 129 + j];
#pragma unroll
    for (int qq = 0; qq < 20; ++qq) m[qq] += w * Ash[j][qq];
    c0 += w * Ash[j][20];
  }
#pragma unroll
  for (int qq = 0; qq < 20; ++qq) Mt[qq * 128 + o] = m[qq];
  C0[o] = c0;
  Wnt[o] = fuse_w[o * 129 + 128];
  // b67 = fm_w1 @ g2e_b2 + fm_b1 (ea2 has no relu before fm_w1; fold valid)
  float sb = 0.f;
  for (int j = 0; j < 128; ++j) sb += fm_w1[o * 128 + j] * g2e_b2[j];
  b67[o] = sb + fm_b1[o];
}

// ---- fold fm_w1 @ g2e_w2 -> W67f (128 blocks: well-parallelized; doing this
// inside k_pack's 4 blocks cost 60us in r9) ----
__global__ void k_fold2(const float* __restrict__ w6, const float* __restrict__ w7,
                        float* __restrict__ W67) {
  int o = blockIdx.x;    // 128
  int k = threadIdx.x;   // 128
  float s = 0.f;
  for (int j = 0; j < 128; ++j) s += w7[o * 128 + j] * w6[j * 128 + k];
  W67[o * 128 + k] = s;
}

// ---- pack weights [128][Kin] into bf16 B-fragment order ----
struct PackArgs {
  const float* src[6];
  u16* dst[6];
  int Kin[6];
  int ksCum[7];
};

__global__ void k_pack(PackArgs pa) {
  int bk = blockIdx.x;
  int mi = 0;
  while (bk >= pa.ksCum[mi + 1]) ++mi;
  int ks = bk - pa.ksCum[mi];
  const float* W = pa.src[mi];
  u16* D = pa.dst[mi] + ks * 4096;
  int Kin = pa.Kin[mi];
#pragma unroll
  for (int t = 0; t < 16; ++t) {
    int el = t * 256 + (int)threadIdx.x;
    int j = el & 7, ln = (el >> 3) & 63, ntile = el >> 9;
    int k = ks * 32 + ((ln >> 4) << 3) + j;
    int n = ntile * 16 + (ln & 15);
    float v = (k < Kin) ? W[n * Kin + k] : 0.0f;
    D[el] = f2bf(v);
  }
}

// ---- node encoder: 16 nodes per block ----
__global__ __launch_bounds__(256) void k_encode(const float* __restrict__ x,
                                                const float* __restrict__ node_type,
                                                const float* __restrict__ Mt,
                                                const float* __restrict__ C0,
                                                const float* __restrict__ Wnt,
                                                u16* __restrict__ h2) {
  __shared__ float xs[16][20], nts[16], mts[20 * 128];
  const int tid = threadIdx.x;
  const int n0 = blockIdx.x * 16;
  for (int i = tid; i < 320; i += 256) xs[i / 20][i % 20] = x[n0 * 20 + i];
  if (tid < 16) nts[tid] = node_type[n0 + tid];
  for (int i = tid; i < 2560; i += 256) mts[i] = Mt[i];
  __syncthreads();
  const int nl = tid >> 4;          // node in block
  const int c0 = (tid & 15) * 8;    // 8 consecutive channels
  float nt = nts[nl];
  union { u16 s[8]; uint4 u; } o;
#pragma unroll
  for (int i = 0; i < 8; ++i) {
    int ch = c0 + i;
    float acc = C0[ch] + Wnt[ch] * nt;
#pragma unroll
    for (int qq = 0; qq < 20; ++qq) acc += xs[nl][qq] * mts[qq * 128 + ch];
    o.s[i] = f2bf(acc);
  }
  *(uint4*)(h2 + (size_t)(n0 + nl) * HID + c0) = o.u;
}

// ---- gnn1: 2 LDS buffers -> 4 blocks/CU. ea1 = g1e(h2r,h2c,ea); h3 (blocks<313) ----
__global__ __launch_bounds__(256, 4) void k_gnn1(
    const int* __restrict__ eidx, const float* __restrict__ eattr,
    const u16* __restrict__ h2, const u16* __restrict__ pW1, const u16* __restrict__ pW2,
    const u16* __restrict__ pW3, const u16* __restrict__ pW4, const float* __restrict__ b1,
    const float* __restrict__ b2, const float* __restrict__ b3, const float* __restrict__ b4,
    u16* __restrict__ ea1, u16* __restrict__ h3) {
  __shared__ __align__(16) u16 B0[64 * STR], B1[64 * STR];
  const int tid = threadIdx.x, lane = tid & 63, wave = tid >> 6;
  const int e0 = blockIdx.x * 64;
  const int m = lane & 15, q = lane >> 4;
  const int aoff = m * STR + q * 8;
  const int* rowI = eidx;
  const int* colI = eidx + N_EDGES;

  stage_gather(rowI, colI, h2, B0, B1, e0, lane, wave);

  // eattr A-frags in registers (K-step 8 of GEMM1)
  bf16x8 ef[4];
#pragma unroll
  for (int mt = 0; mt < 4; ++mt) {
    union { u16 s[8]; uint4 u; bf16x8 v; } t;
    t.u = make_uint4(0u, 0u, 0u, 0u);
    if (q == 0) {
      float4 a = *(const float4*)(eattr + (size_t)(e0 + mt * 16 + m) * 4);
      t.s[0] = f2bf(a.x); t.s[1] = f2bf(a.y); t.s[2] = f2bf(a.z); t.s[3] = f2bf(a.w);
    }
    ef[mt] = t.v;
  }
  __syncthreads();  // S1

  f32x4 acc[4][2];
  zero_acc(acc);  // GEMM1: K=288: [B0 h2r | B1 h2c | eattr-regs]
  wgemm<9>(pW1, [&](int ks, int mt) -> bf16x8 {
    if (ks < 4) return ld8(B0 + aoff + mt * 16 * STR + ks * 32);
    if (ks < 8) return ld8(B1 + aoff + mt * 16 * STR + (ks - 4) * 32);
    return ef[mt];
  }, acc, lane, wave);
  __syncthreads();  // S2: all B0/B1 reads done
  epi_store<true>(B1, acc, b1, lane, wave);  // H -> B1 (h2c dead)
  __syncthreads();  // S3

  zero_acc(acc);  // GEMM2: ea1 = W2 x H
  wgemm<4>(pW2, [&](int ks, int mt) -> bf16x8 {
    return ld8(B1 + aoff + mt * 16 * STR + ks * 32);
  }, acc, lane, wave);
  epi_store<false>(B0, acc, b2, lane, wave);  // ea1 -> B0 (h2r dead since S2)
  __syncthreads();  // S4
  flush_buf(B0, ea1, e0, tid);

  if (e0 < N_NODES) {  // h3 only ever gathered at indices < N
    // re-gather h2row -> B1 (H dead after GEMM2; safe after S4). L2-hit, 313 blocks.
#pragma unroll
    for (int it = 0; it < 4; ++it) {
      int e = wave * 16 + it * 4 + q;  // 0..63
      int id = rowI[e0 + e];
      uint4 v = *(const uint4*)(h2 + (size_t)id * HID + m * 8);
      *(uint4*)(B1 + e * STR + m * 8) = v;
    }
    __syncthreads();  // S5

    zero_acc(acc);  // GEMM3: K=256: [B1 h2row | B0 ea1]
    wgemm<8>(pW3, [&](int ks, int mt) -> bf16x8 {
      if (ks < 4) return ld8(B1 + aoff + mt * 16 * STR + ks * 32);
      return ld8(B0 + aoff + mt * 16 * STR + (ks - 4) * 32);
    }, acc, lane, wave);
    __syncthreads();  // S6: all B0/B1 reads done (flush also long done)
    epi_store<true>(B1, acc, b3, lane, wave);  // H' -> B1
    __syncthreads();  // S7

    zero_acc(acc);  // GEMM4: h3 = W4 x H'
    wgemm<4>(pW4, [&](int ks, int mt) -> bf16x8 {
      return ld8(B1 + aoff + mt * 16 * STR + ks * 32);
    }, acc, lane, wave);
    epi_store<false>(B0, acc, b4, lane, wave);  // h3 -> B0 (ea1 dead since S6)
    __syncthreads();  // S8
    flush_buf(B0, h3, e0, tid);
  }
}

// ---- gnn2 (folded W67) + BN stats via per-block partials (NOT atomics: 200k
// same-line atomics serialized L2 and doubled this kernel in r8) ----
__global__ __launch_bounds__(256, 4) void k_gnn2(
    const int* __restrict__ eidx, const u16* __restrict__ h3, u16* ea1z,
    const u16* __restrict__ pW5, const u16* __restrict__ pW67,
    const float* __restrict__ b5, const float* __restrict__ b67,
    float* __restrict__ partials) {
  __shared__ __align__(16) u16 B0[64 * STR], B1[64 * STR];
  const int tid = threadIdx.x, lane = tid & 63, wave = tid >> 6;
  const int e0 = blockIdx.x * 64;
  const int m = lane & 15, q = lane >> 4;
  const int aoff = m * STR + q * 8;
  const int* rowI = eidx;
  const int* colI = eidx + N_EDGES;

  stage_gather(rowI, colI, h3, B0, B1, e0, lane, wave);
  __syncthreads();  // S1

  f32x4 acc[4][2];
  zero_acc(acc);  // GEMM1a: ks 0..7 of K=384: [B0 h3r | B1 h3c]
  wgemm<8>(pW5, [&](int ks, int mt) -> bf16x8 {
    if (ks < 4) return ld8(B0 + aoff + mt * 16 * STR + ks * 32);
    return ld8(B1 + aoff + mt * 16 * STR + (ks - 4) * 32);
  }, acc, lane, wave);
  __syncthreads();  // S2: all B0/B1 reads done

  // stage ea1 (own rows, coalesced) -> B0 (h3r dead)
#pragma unroll
  for (int it = 0; it < 4; ++it) {
    int cid = tid + it * 256, e = cid >> 4, p = cid & 15;
    uint4 v = *(const uint4*)(ea1z + (size_t)(e0 + e) * HID + p * 8);
    *(uint4*)(B0 + e * STR + p * 8) = v;
  }
  __syncthreads();  // S3

  // GEMM1b: ks 8..11 (ea1 part), accumulate into same acc
  wgemm<4>(pW5 + 8 * 4096, [&](int ks, int mt) -> bf16x8 {
    return ld8(B0 + aoff + mt * 16 * STR + ks * 32);
  }, acc, lane, wave);
  epi_store<true>(B1, acc, b5, lane, wave);  // H -> B1 (h3c dead since S2)
  __syncthreads();  // S4

  zero_acc(acc);  // GEMM2': z = (fm_w1 @ g2e_w2) @ H + b67
  wgemm<4>(pW67, [&](int ks, int mt) -> bf16x8 {
    return ld8(B1 + aoff + mt * 16 * STR + ks * 32);
  }, acc, lane, wave);

  // z epilogue -> B0 + per-channel BN partials (wave covers ch wave*32..+31)
  {
    const int c = lane & 15;
    const float bb0 = b67[wave * 32 + c], bb1 = b67[wave * 32 + 16 + c];
    float s0 = 0.f, q0 = 0.f, s1 = 0.f, q1 = 0.f;
#pragma unroll
    for (int mt = 0; mt < 4; ++mt)
#pragma unroll
      for (int r = 0; r < 4; ++r) {
        float v0 = acc[mt][0][r] + bb0;
        float v1 = acc[mt][1][r] + bb1;
        s0 += v0; q0 += v0 * v0;
        s1 += v1; q1 += v1 * v1;
        int row = mt * 16 + q * 4 + r;
        B0[row * STR + wave * 32 + c] = f2bf(v0);
        B0[row * STR + wave * 32 + 16 + c] = f2bf(v1);
      }
    s0 += __shfl_xor(s0, 16); s0 += __shfl_xor(s0, 32);
    q0 += __shfl_xor(q0, 16); q0 += __shfl_xor(q0, 32);
    s1 += __shfl_xor(s1, 16); s1 += __shfl_xor(s1, 32);
    q1 += __shfl_xor(q1, 16); q1 += __shfl_xor(q1, 32);
    if (lane < 16) {
      int base = (int)blockIdx.x * 256;
      partials[base + wave * 32 + lane] = s0;
      partials[base + wave * 32 + 16 + lane] = s1;
      partials[base + 128 + wave * 32 + lane] = q0;
      partials[base + 128 + wave * 32 + 16 + lane] = q1;
    }
  }
  __syncthreads();  // S5
  flush_buf(B0, ea1z, e0, tid);  // z overwrites own ea1 rows (already consumed)
}

__global__ void k_reduce(const float* __restrict__ partials, float* __restrict__ bnacc,
                         int nrows) {
  int t = threadIdx.x;  // 256
  float s = 0.f;
  for (int b = blockIdx.x; b < nrows; b += 64) s += partials[b * 256 + t];
  atomicAdd(&bnacc[t], s);
}

// ---- head: one edge per thread; BN finalize recomputed per block (cheap) ----
__global__ __launch_bounds__(256) void k_head(const u16* __restrict__ z,
                                              const float* __restrict__ bnacc,
                                              const float* __restrict__ bn_g,
                                              const float* __restrict__ bn_b,
                                              const float* __restrict__ w2,
                                              const float* __restrict__ b2,
                                              float* __restrict__ out) {
  __shared__ float sh_s[128], sh_h[128], sh_w0[128], sh_w1[128], sh_w2[128];
  const int tid = threadIdx.x;
  if (tid < 128) {
    const float inv = 1.0f / (float)N_EDGES;
    float mu = bnacc[tid] * inv;
    float var = bnacc[128 + tid] * inv - mu * mu;
    float sc = bn_g[tid] * rsqrtf(var + 1e-5f);
    sh_s[tid] = sc;
    sh_h[tid] = bn_b[tid] - mu * sc;
    sh_w0[tid] = w2[tid];
    sh_w1[tid] = w2[128 + tid];
    sh_w2[tid] = w2[256 + tid];
  }
  __syncthreads();
  const int e = blockIdx.x * 256 + tid;
  if (e >= N_EDGES) return;
  float a0 = b2[0], a1 = b2[1], a2 = b2[2];
  const u16* zr = z + (size_t)e * HID;
#pragma unroll
  for (int p = 0; p < 16; ++p) {
    uint4 v = *(const uint4*)(zr + p * 8);
    unsigned wv[4] = {v.x, v.y, v.z, v.w};
#pragma unroll
    for (int k = 0; k < 4; ++k) {
      int ch = p * 8 + k * 2;
      float lo = bf2f(wv[k] & 0xffffu), hi = bf2f(wv[k] >> 16);
      float r0 = fmaxf(fmaf(lo, sh_s[ch], sh_h[ch]), 0.f);
      float r1 = fmaxf(fmaf(hi, sh_s[ch + 1], sh_h[ch + 1]), 0.f);
      a0 += r0 * sh_w0[ch] + r1 * sh_w0[ch + 1];
      a1 += r0 * sh_w1[ch] + r1 * sh_w1[ch + 1];
      a2 += r0 * sh_w2[ch] + r1 * sh_w2[ch + 1];
    }
  }
  out[e * 3 + 0] = a0;
  out[e * 3 + 1] = a1;
  out[e * 3 + 2] = a2;
}

extern "C" void kernel_launch(void* const* d_in, const int* in_sizes, int n_in,
                              void* d_out, int out_size, void* d_ws, size_t ws_size,
                              hipStream_t stream) {
  const float* x         = (const float*)d_in[0];
  const int* eidx        = (const int*)d_in[1];
  const float* eattr     = (const float*)d_in[2];
  const float* node_type = (const float*)d_in[4];
  const float* emb       = (const float*)d_in[5];
  const float* conv_w    = (const float*)d_in[6];
  const float* conv_b    = (const float*)d_in[7];
  const float* fuse_w    = (const float*)d_in[8];
  const float* fuse_b    = (const float*)d_in[9];
  const float* g1e_w1    = (const float*)d_in[10];
  const float* g1e_b1    = (const float*)d_in[11];
  const float* g1e_w2    = (const float*)d_in[12];
  const float* g1e_b2    = (const float*)d_in[13];
  const float* g1n_w1    = (const float*)d_in[14];
  const float* g1n_b1    = (const float*)d_in[15];
  const float* g1n_w2    = (const float*)d_in[16];
  const float* g1n_b2    = (const float*)d_in[17];
  const float* g2e_w1    = (const float*)d_in[18];
  const float* g2e_b1    = (const float*)d_in[19];
  const float* g2e_w2    = (const float*)d_in[20];
  const float* g2e_b2    = (const float*)d_in[21];
  // d_in[22..25] = g2n_* : dead code in the reference (output unused)
  const float* fm_w1     = (const float*)d_in[26];
  const float* fm_b1     = (const float*)d_in[27];
  const float* bn_g      = (const float*)d_in[28];
  const float* bn_b      = (const float*)d_in[29];
  const float* fm_w2     = (const float*)d_in[30];
  const float* fm_b2     = (const float*)d_in[31];
  float* out = (float*)d_out;

  char* ws = (char*)d_ws;
  size_t off = 0;
  auto take = [&](size_t bytes) {
    void* p = ws + off;
    off = (off + bytes + 255) & ~(size_t)255;
    return p;
  };
  u16* h2   = (u16*)take((size_t)N_NODES * HID * 2);
  u16* h3   = (u16*)take((size_t)20032 * HID * 2);  // only rows < N ever gathered
  u16* ea1z = (u16*)take((size_t)N_EDGES * HID * 2);
  float* Mt    = (float*)take(20 * 128 * 4);
  float* C0    = (float*)take(128 * 4);
  float* Wnt   = (float*)take(128 * 4);
  float* bnacc = (float*)take(256 * 4);
  float* b67   = (float*)take(128 * 4);
  float* W67f  = (float*)take(128 * 128 * 4);
  float* partials = (float*)take((size_t)NBLK * 256 * 4);
  u16* pW1  = (u16*)take(9 * 4096 * 2);
  u16* pW2  = (u16*)take(4 * 4096 * 2);
  u16* pW3  = (u16*)take(8 * 4096 * 2);
  u16* pW4  = (u16*)take(4 * 4096 * 2);
  u16* pW5  = (u16*)take(12 * 4096 * 2);
  u16* pW67 = (u16*)take(4 * 4096 * 2);

  hipMemsetAsync(bnacc, 0, 256 * 4, stream);
  k_fold<<<1, 128, 0, stream>>>(emb, conv_w, conv_b, fuse_w, fuse_b,
                                fm_w1, g2e_b2, fm_b1, Mt, C0, Wnt, b67);
  k_fold2<<<128, 128, 0, stream>>>(g2e_w2, fm_w1, W67f);

  PackArgs pa;
  const float* srcs[6] = {g1e_w1, g1e_w2, g1n_w1, g1n_w2, g2e_w1, W67f};
  u16* dsts[6] = {pW1, pW2, pW3, pW4, pW5, pW67};
  int kins[6] = {260, 128, 256, 128, 384, 128};
  int kst[6] = {9, 4, 8, 4, 12, 4};
  int cum = 0;
  for (int i = 0; i < 6; ++i) {
    pa.src[i] = srcs[i]; pa.dst[i] = dsts[i]; pa.Kin[i] = kins[i];
    pa.ksCum[i] = cum; cum += kst[i];
  }
  pa.ksCum[6] = cum;  // 41
  k_pack<<<41, 256, 0, stream>>>(pa);

  k_encode<<<N_NODES / 16, 256, 0, stream>>>(x, node_type, Mt, C0, Wnt, h2);
  k_gnn1<<<NBLK, 256, 0, stream>>>(eidx, eattr, h2, pW1, pW2, pW3, pW4,
                                   g1e_b1, g1e_b2, g1n_b1, g1n_b2, ea1z, h3);
  k_gnn2<<<NBLK, 256, 0, stream>>>(eidx, h3, ea1z, pW5, pW67,
                                   g2e_b1, b67, partials);
  k_reduce<<<64, 256, 0, stream>>>(partials, bnacc, NBLK);
  k_head<<<(N_EDGES + 255) / 256, 256, 0, stream>>>(ea1z, bnacc, bn_g, bn_b,
                                                    fm_w2, fm_b2, out);
}

// Round 11
// 237.530 us; speedup vs baseline: 1.4743x; 1.1674x over previous
//
#include <hip/hip_runtime.h>

#define N_NODES 20000
#define N_EDGES 200000
#define HID 128
#define STR 136   // LDS row stride in u16: 272B rows -> every b128 access 16B-aligned
#define NBLK 3125 // 64-edge tiles
#define NREP 64   // BN accumulator replicas

typedef unsigned short u16;
using bf16x8 = __attribute__((ext_vector_type(8))) __bf16;
using f32x4  = __attribute__((ext_vector_type(4))) float;

__device__ __forceinline__ u16 f2bf(float f) {
  union { float f; unsigned u; } v; v.f = f;
  unsigned u = v.u;
  return (u16)((u + 0x7FFFu + ((u >> 16) & 1u)) >> 16);
}
__device__ __forceinline__ float bf2f(unsigned s) {
  union { unsigned u; float f; } v; v.u = s << 16;
  return v.f;
}
__device__ __forceinline__ bf16x8 ld8(const u16* p) { return *(const bf16x8*)p; }

__device__ __forceinline__ void zero_acc(f32x4 acc[4][2]) {
#pragma unroll
  for (int i = 0; i < 4; ++i) {
    acc[i][0] = (f32x4){0.f, 0.f, 0.f, 0.f};
    acc[i][1] = (f32x4){0.f, 0.f, 0.f, 0.f};
  }
}

template <int KSTEPS, typename AF>
__device__ __forceinline__ void wgemm(const u16* __restrict__ PW, AF afrag,
                                      f32x4 acc[4][2], int lane, int wave) {
  const u16* pb = PW + (wave * 2 * 64 + lane) * 8;
  bf16x8 b0[2], b1[2];
  b0[0] = ld8(pb);
  b1[0] = ld8(pb + 512);
#pragma unroll
  for (int ks = 0; ks < KSTEPS; ++ks) {
    const int cur = ks & 1, nxt = cur ^ 1;
    if (ks + 1 < KSTEPS) {
      b0[nxt] = ld8(pb + (ks + 1) * 4096);
      b1[nxt] = ld8(pb + (ks + 1) * 4096 + 512);
    }
#pragma unroll
    for (int mt = 0; mt < 4; ++mt) {
      bf16x8 a = afrag(ks, mt);
      acc[mt][0] = __builtin_amdgcn_mfma_f32_16x16x32_bf16(a, b0[cur], acc[mt][0], 0, 0, 0);
      acc[mt][1] = __builtin_amdgcn_mfma_f32_16x16x32_bf16(a, b1[cur], acc[mt][1], 0, 0, 0);
    }
  }
}

// C/D: row(edge) = mt*16 + (lane>>4)*4 + r, col(ch) = wave*32 + nt*16 + (lane&15).
template <bool RELU>
__device__ __forceinline__ void epi_store(u16* buf, const f32x4 acc[4][2],
                                          const float* __restrict__ bias,
                                          int lane, int wave) {
  const int c = lane & 15, q = lane >> 4;
  const float bb0 = bias[wave * 32 + c], bb1 = bias[wave * 32 + 16 + c];
#pragma unroll
  for (int mt = 0; mt < 4; ++mt)
#pragma unroll
    for (int nt = 0; nt < 2; ++nt) {
      const float bb = nt ? bb1 : bb0;
      const int col = wave * 32 + nt * 16 + c;
#pragma unroll
      for (int r = 0; r < 4; ++r) {
        float v = acc[mt][nt][r] + bb;
        if (RELU) v = fmaxf(v, 0.f);
        buf[(mt * 16 + q * 4 + r) * STR + col] = f2bf(v);
      }
    }
}

__device__ __forceinline__ void flush_buf(const u16* buf, u16* __restrict__ gout,
                                          int e0, int tid) {
#pragma unroll
  for (int it = 0; it < 4; ++it) {
    int cid = tid + it * 256, e = cid >> 4, p = cid & 15;
    uint4 v = *(const uint4*)(buf + e * STR + p * 8);
    *(uint4*)(gout + (size_t)(e0 + e) * HID + p * 8) = v;
  }
}

// TA-friendly gather: 16 lanes cooperate per row -> 8 distinct lines/instr.
__device__ __forceinline__ void stage_gather(const int* __restrict__ rowI,
                                             const int* __restrict__ colI,
                                             const u16* __restrict__ htab,
                                             u16* B0, u16* B1,
                                             int e0, int lane, int wave) {
  const int r = lane >> 4, p = lane & 15;
#pragma unroll
  for (int it = 0; it < 8; ++it) {
    int j = wave * 32 + it * 4 + r;  // 0..127
    int e = j & 63;
    int id = (j < 64) ? rowI[e0 + e] : colI[e0 + e];
    uint4 v = *(const uint4*)(htab + (size_t)id * HID + p * 8);
    *(uint4*)(((j < 64) ? B0 : B1) + e * STR + p * 8) = v;
  }
}

// ---- prep1: one block per output channel o. Folds encoder+fuse (Mt,C0,Wnt),
// b67, and W67 row o. Replaces the serial 1-block k_fold + k_fold2. ----
__global__ __launch_bounds__(128) void k_prep1(
    const float* __restrict__ emb, const float* __restrict__ conv_w,
    const float* __restrict__ conv_b, const float* __restrict__ fuse_w,
    const float* __restrict__ fuse_b,
    const float* __restrict__ fm_w1, const float* __restrict__ g2e_b2,
    const float* __restrict__ fm_b1, const float* __restrict__ w6,
    float* __restrict__ Mt, float* __restrict__ C0, float* __restrict__ Wnt,
    float* __restrict__ b67, float* __restrict__ W67) {
  __shared__ float red[22][129];
  __shared__ float w7s[128];
  const int o = blockIdx.x;   // 0..127
  const int j = threadIdx.x;  // 0..127
  // thread j: Ash row j (conv fold), then products with fuse_w[o][j]
  float A[21];
  {
    float b0 = conv_b[j];
#pragma unroll
    for (int p = 0; p < 5; ++p) {
#pragma unroll
      for (int i = 0; i < 8; ++i) {
        float s = 0.f;
#pragma unroll
        for (int k = 0; k < 3; ++k) {
          int t = p + 1 - k;
          if (t >= 0 && t < 5) s += conv_w[(j * 8 + i) * 3 + k];
        }
        s *= 0.2f;
        if (i < 4) A[p * 4 + i] = s;
        else b0 += emb[p * 4 + (i - 4)] * s;
      }
    }
    A[20] = b0;
  }
  float w = fuse_w[o * 129 + j];   // coalesced across j
  float w7 = fm_w1[o * 128 + j];
  w7s[j] = w7;
#pragma unroll
  for (int qq = 0; qq < 21; ++qq) red[qq][j] = w * A[qq];
  red[21][j] = w7 * g2e_b2[j];
  __syncthreads();
  if (j < 22) {
    float s = 0.f;
    for (int t = 0; t < 128; ++t) s += red[j][t];
    if (j < 20)      Mt[j * 128 + o] = s;
    else if (j == 20) C0[o] = s + fuse_b[o];
    else              b67[o] = s + fm_b1[o];
  }
  if (j == 0) Wnt[o] = fuse_w[o * 129 + 128];
  // W67 row o: thread k = j
  float s = 0.f;
  for (int t = 0; t < 128; ++t) s += w7s[t] * w6[t * 128 + j];
  W67[o * 128 + j] = s;
}

// ---- prep2: blocks 0..40 pack weights; blocks 41.. encode nodes ----
struct PackArgs {
  const float* src[6];
  u16* dst[6];
  int Kin[6];
  int ksCum[7];
};

__global__ __launch_bounds__(256) void k_prep2(
    PackArgs pa, const float* __restrict__ x, const float* __restrict__ node_type,
    const float* __restrict__ Mt, const float* __restrict__ C0,
    const float* __restrict__ Wnt, u16* __restrict__ h2) {
  if (blockIdx.x < 41) {  // ---- pack branch ----
    int bk = blockIdx.x;
    int mi = 0;
    while (bk >= pa.ksCum[mi + 1]) ++mi;
    int ks = bk - pa.ksCum[mi];
    const float* W = pa.src[mi];
    u16* D = pa.dst[mi] + ks * 4096;
    int Kin = pa.Kin[mi];
#pragma unroll
    for (int t = 0; t < 16; ++t) {
      int el = t * 256 + (int)threadIdx.x;
      int j = el & 7, ln = (el >> 3) & 63, ntile = el >> 9;
      int k = ks * 32 + ((ln >> 4) << 3) + j;
      int n = ntile * 16 + (ln & 15);
      float v = (k < Kin) ? W[n * Kin + k] : 0.0f;
      D[el] = f2bf(v);
    }
    return;
  }
  // ---- encode branch: 16 nodes per block ----
  __shared__ float xs[16][20], nts[16], mts[20 * 128];
  const int tid = threadIdx.x;
  const int n0 = ((int)blockIdx.x - 41) * 16;
  for (int i = tid; i < 320; i += 256) xs[i / 20][i % 20] = x[n0 * 20 + i];
  if (tid < 16) nts[tid] = node_type[n0 + tid];
  for (int i = tid; i < 2560; i += 256) mts[i] = Mt[i];
  __syncthreads();
  const int nl = tid >> 4;
  const int c0 = (tid & 15) * 8;
  float nt = nts[nl];
  union { u16 s[8]; uint4 u; } o;
#pragma unroll
  for (int i = 0; i < 8; ++i) {
    int ch = c0 + i;
    float acc = C0[ch] + Wnt[ch] * nt;
#pragma unroll
    for (int qq = 0; qq < 20; ++qq) acc += xs[nl][qq] * mts[qq * 128 + ch];
    o.s[i] = f2bf(acc);
  }
  *(uint4*)(h2 + (size_t)(n0 + nl) * HID + c0) = o.u;
}

// ---- gnn1: unchanged from r10 (proven) ----
__global__ __launch_bounds__(256, 4) void k_gnn1(
    const int* __restrict__ eidx, const float* __restrict__ eattr,
    const u16* __restrict__ h2, const u16* __restrict__ pW1, const u16* __restrict__ pW2,
    const u16* __restrict__ pW3, const u16* __restrict__ pW4, const float* __restrict__ b1,
    const float* __restrict__ b2, const float* __restrict__ b3, const float* __restrict__ b4,
    u16* __restrict__ ea1, u16* __restrict__ h3) {
  __shared__ __align__(16) u16 B0[64 * STR], B1[64 * STR];
  const int tid = threadIdx.x, lane = tid & 63, wave = tid >> 6;
  const int e0 = blockIdx.x * 64;
  const int m = lane & 15, q = lane >> 4;
  const int aoff = m * STR + q * 8;
  const int* rowI = eidx;
  const int* colI = eidx + N_EDGES;

  stage_gather(rowI, colI, h2, B0, B1, e0, lane, wave);

  bf16x8 ef[4];
#pragma unroll
  for (int mt = 0; mt < 4; ++mt) {
    union { u16 s[8]; uint4 u; bf16x8 v; } t;
    t.u = make_uint4(0u, 0u, 0u, 0u);
    if (q == 0) {
      float4 a = *(const float4*)(eattr + (size_t)(e0 + mt * 16 + m) * 4);
      t.s[0] = f2bf(a.x); t.s[1] = f2bf(a.y); t.s[2] = f2bf(a.z); t.s[3] = f2bf(a.w);
    }
    ef[mt] = t.v;
  }
  __syncthreads();  // S1

  f32x4 acc[4][2];
  zero_acc(acc);  // GEMM1: K=288: [B0 h2r | B1 h2c | eattr-regs]
  wgemm<9>(pW1, [&](int ks, int mt) -> bf16x8 {
    if (ks < 4) return ld8(B0 + aoff + mt * 16 * STR + ks * 32);
    if (ks < 8) return ld8(B1 + aoff + mt * 16 * STR + (ks - 4) * 32);
    return ef[mt];
  }, acc, lane, wave);
  __syncthreads();  // S2
  epi_store<true>(B1, acc, b1, lane, wave);  // H -> B1
  __syncthreads();  // S3

  zero_acc(acc);  // GEMM2: ea1 = W2 x H
  wgemm<4>(pW2, [&](int ks, int mt) -> bf16x8 {
    return ld8(B1 + aoff + mt * 16 * STR + ks * 32);
  }, acc, lane, wave);
  epi_store<false>(B0, acc, b2, lane, wave);  // ea1 -> B0
  __syncthreads();  // S4
  flush_buf(B0, ea1, e0, tid);

  if (e0 < N_NODES) {
#pragma unroll
    for (int it = 0; it < 4; ++it) {
      int e = wave * 16 + it * 4 + q;
      int id = rowI[e0 + e];
      uint4 v = *(const uint4*)(h2 + (size_t)id * HID + m * 8);
      *(uint4*)(B1 + e * STR + m * 8) = v;
    }
    __syncthreads();  // S5

    zero_acc(acc);  // GEMM3: K=256: [B1 h2row | B0 ea1]
    wgemm<8>(pW3, [&](int ks, int mt) -> bf16x8 {
      if (ks < 4) return ld8(B1 + aoff + mt * 16 * STR + ks * 32);
      return ld8(B0 + aoff + mt * 16 * STR + (ks - 4) * 32);
    }, acc, lane, wave);
    __syncthreads();  // S6
    epi_store<true>(B1, acc, b3, lane, wave);  // H' -> B1
    __syncthreads();  // S7

    zero_acc(acc);  // GEMM4
    wgemm<4>(pW4, [&](int ks, int mt) -> bf16x8 {
      return ld8(B1 + aoff + mt * 16 * STR + ks * 32);
    }, acc, lane, wave);
    epi_store<false>(B0, acc, b4, lane, wave);  // h3 -> B0
    __syncthreads();  // S8
    flush_buf(B0, h3, e0, tid);
  }
}

// ---- gnn2: BN partials -> 64-replica atomic accumulator (16K addresses,
// ~49 adds each; r8's failure was 256 addresses x 3125 adds) ----
__global__ __launch_bounds__(256, 4) void k_gnn2(
    const int* __restrict__ eidx, const u16* __restrict__ h3, u16* ea1z,
    const u16* __restrict__ pW5, const u16* __restrict__ pW67,
    const float* __restrict__ b5, const float* __restrict__ b67,
    float* __restrict__ bnrep) {
  __shared__ __align__(16) u16 B0[64 * STR], B1[64 * STR];
  const int tid = threadIdx.x, lane = tid & 63, wave = tid >> 6;
  const int e0 = blockIdx.x * 64;
  const int m = lane & 15, q = lane >> 4;
  const int aoff = m * STR + q * 8;
  const int* rowI = eidx;
  const int* colI = eidx + N_EDGES;

  stage_gather(rowI, colI, h3, B0, B1, e0, lane, wave);
  __syncthreads();  // S1

  f32x4 acc[4][2];
  zero_acc(acc);  // GEMM1a: ks 0..7 of K=384
  wgemm<8>(pW5, [&](int ks, int mt) -> bf16x8 {
    if (ks < 4) return ld8(B0 + aoff + mt * 16 * STR + ks * 32);
    return ld8(B1 + aoff + mt * 16 * STR + (ks - 4) * 32);
  }, acc, lane, wave);
  __syncthreads();  // S2

#pragma unroll
  for (int it = 0; it < 4; ++it) {
    int cid = tid + it * 256, e = cid >> 4, p = cid & 15;
    uint4 v = *(const uint4*)(ea1z + (size_t)(e0 + e) * HID + p * 8);
    *(uint4*)(B0 + e * STR + p * 8) = v;
  }
  __syncthreads();  // S3

  wgemm<4>(pW5 + 8 * 4096, [&](int ks, int mt) -> bf16x8 {
    return ld8(B0 + aoff + mt * 16 * STR + ks * 32);
  }, acc, lane, wave);
  epi_store<true>(B1, acc, b5, lane, wave);  // H -> B1
  __syncthreads();  // S4

  zero_acc(acc);  // GEMM2': z = W67 @ H + b67
  wgemm<4>(pW67, [&](int ks, int mt) -> bf16x8 {
    return ld8(B1 + aoff + mt * 16 * STR + ks * 32);
  }, acc, lane, wave);

  {
    const int c = lane & 15;
    const float bb0 = b67[wave * 32 + c], bb1 = b67[wave * 32 + 16 + c];
    float s0 = 0.f, q0 = 0.f, s1 = 0.f, q1 = 0.f;
#pragma unroll
    for (int mt = 0; mt < 4; ++mt)
#pragma unroll
      for (int r = 0; r < 4; ++r) {
        float v0 = acc[mt][0][r] + bb0;
        float v1 = acc[mt][1][r] + bb1;
        s0 += v0; q0 += v0 * v0;
        s1 += v1; q1 += v1 * v1;
        int row = mt * 16 + q * 4 + r;
        B0[row * STR + wave * 32 + c] = f2bf(v0);
        B0[row * STR + wave * 32 + 16 + c] = f2bf(v1);
      }
    s0 += __shfl_xor(s0, 16); s0 += __shfl_xor(s0, 32);
    q0 += __shfl_xor(q0, 16); q0 += __shfl_xor(q0, 32);
    s1 += __shfl_xor(s1, 16); s1 += __shfl_xor(s1, 32);
    q1 += __shfl_xor(q1, 16); q1 += __shfl_xor(q1, 32);
    if (lane < 16) {
      float* slot = bnrep + ((int)blockIdx.x & (NREP - 1)) * 256;
      atomicAdd(&slot[wave * 32 + lane], s0);
      atomicAdd(&slot[wave * 32 + 16 + lane], s1);
      atomicAdd(&slot[128 + wave * 32 + lane], q0);
      atomicAdd(&slot[128 + wave * 32 + 16 + lane], q1);
    }
  }
  __syncthreads();  // S5
  flush_buf(B0, ea1z, e0, tid);
}

// ---- head: cooperative (16 lanes per edge -> 16 lines/wave-instr, not 64);
// BN finalize from replica sum per block ----
__global__ __launch_bounds__(256) void k_head(const u16* __restrict__ z,
                                              const float* __restrict__ bnrep,
                                              const float* __restrict__ bn_g,
                                              const float* __restrict__ bn_b,
                                              const float* __restrict__ w2,
                                              const float* __restrict__ b2,
                                              float* __restrict__ out) {
  __shared__ float sh_s[128], sh_h[128], sh_w0[128], sh_w1[128], sh_w2[128];
  const int tid = threadIdx.x;
  {
    float s = 0.f;
    for (int r = 0; r < NREP; ++r) s += bnrep[r * 256 + tid];
    __shared__ float acc2[256];
    acc2[tid] = s;
    __syncthreads();
    if (tid < 128) {
      const float inv = 1.0f / (float)N_EDGES;
      float mu = acc2[tid] * inv;
      float var = acc2[128 + tid] * inv - mu * mu;
      float sc = bn_g[tid] * rsqrtf(var + 1e-5f);
      sh_s[tid] = sc;
      sh_h[tid] = bn_b[tid] - mu * sc;
      sh_w0[tid] = w2[tid];
      sh_w1[tid] = w2[128 + tid];
      sh_w2[tid] = w2[256 + tid];
    }
    __syncthreads();
  }
  const int lane = tid & 63, wave = tid >> 6;
  const int g = lane >> 4;       // edge-in-quad
  const int p = lane & 15;       // piece
  const int c0 = p * 8;
  const float bb0 = b2[0], bb1 = b2[1], bb2 = b2[2];
#pragma unroll 4
  for (int it = 0; it < 16; ++it) {
    int e = (int)blockIdx.x * 256 + wave * 64 + it * 4 + g;
    if (e >= N_EDGES) break;
    uint4 v = *(const uint4*)(z + (size_t)e * HID + c0);
    unsigned wv[4] = {v.x, v.y, v.z, v.w};
    float a0 = 0.f, a1 = 0.f, a2 = 0.f;
#pragma unroll
    for (int k = 0; k < 4; ++k) {
      int ch = c0 + k * 2;
      float lo = bf2f(wv[k] & 0xffffu), hi = bf2f(wv[k] >> 16);
      float r0 = fmaxf(fmaf(lo, sh_s[ch], sh_h[ch]), 0.f);
      float r1 = fmaxf(fmaf(hi, sh_s[ch + 1], sh_h[ch + 1]), 0.f);
      a0 += r0 * sh_w0[ch] + r1 * sh_w0[ch + 1];
      a1 += r0 * sh_w1[ch] + r1 * sh_w1[ch + 1];
      a2 += r0 * sh_w2[ch] + r1 * sh_w2[ch + 1];
    }
#pragma unroll
    for (int off = 1; off < 16; off <<= 1) {
      a0 += __shfl_xor(a0, off);
      a1 += __shfl_xor(a1, off);
      a2 += __shfl_xor(a2, off);
    }
    if (p < 3) out[e * 3 + p] = (p == 0) ? a0 + bb0 : (p == 1) ? a1 + bb1 : a2 + bb2;
  }
}

extern "C" void kernel_launch(void* const* d_in, const int* in_sizes, int n_in,
                              void* d_out, int out_size, void* d_ws, size_t ws_size,
                              hipStream_t stream) {
  const float* x         = (const float*)d_in[0];
  const int* eidx        = (const int*)d_in[1];
  const float* eattr     = (const float*)d_in[2];
  const float* node_type = (const float*)d_in[4];
  const float* emb       = (const float*)d_in[5];
  const float* conv_w    = (const float*)d_in[6];
  const float* conv_b    = (const float*)d_in[7];
  const float* fuse_w    = (const float*)d_in[8];
  const float* fuse_b    = (const float*)d_in[9];
  const float* g1e_w1    = (const float*)d_in[10];
  const float* g1e_b1    = (const float*)d_in[11];
  const float* g1e_w2    = (const float*)d_in[12];
  const float* g1e_b2    = (const float*)d_in[13];
  const float* g1n_w1    = (const float*)d_in[14];
  const float* g1n_b1    = (const float*)d_in[15];
  const float* g1n_w2    = (const float*)d_in[16];
  const float* g1n_b2    = (const float*)d_in[17];
  const float* g2e_w1    = (const float*)d_in[18];
  const float* g2e_b1    = (const float*)d_in[19];
  const float* g2e_w2    = (const float*)d_in[20];
  const float* g2e_b2    = (const float*)d_in[21];
  // d_in[22..25] = g2n_* : dead code in the reference (output unused)
  const float* fm_w1     = (const float*)d_in[26];
  const float* fm_b1     = (const float*)d_in[27];
  const float* bn_g      = (const float*)d_in[28];
  const float* bn_b      = (const float*)d_in[29];
  const float* fm_w2     = (const float*)d_in[30];
  const float* fm_b2     = (const float*)d_in[31];
  float* out = (float*)d_out;

  char* ws = (char*)d_ws;
  size_t off = 0;
  auto take = [&](size_t bytes) {
    void* p = ws + off;
    off = (off + bytes + 255) & ~(size_t)255;
    return p;
  };
  u16* h2   = (u16*)take((size_t)N_NODES * HID * 2);
  u16* h3   = (u16*)take((size_t)20032 * HID * 2);
  u16* ea1z = (u16*)take((size_t)N_EDGES * HID * 2);
  float* Mt    = (float*)take(20 * 128 * 4);
  float* C0    = (float*)take(128 * 4);
  float* Wnt   = (float*)take(128 * 4);
  float* b67   = (float*)take(128 * 4);
  float* W67f  = (float*)take(128 * 128 * 4);
  float* bnrep = (float*)take((size_t)NREP * 256 * 4);
  u16* pW1  = (u16*)take(9 * 4096 * 2);
  u16* pW2  = (u16*)take(4 * 4096 * 2);
  u16* pW3  = (u16*)take(8 * 4096 * 2);
  u16* pW4  = (u16*)take(4 * 4096 * 2);
  u16* pW5  = (u16*)take(12 * 4096 * 2);
  u16* pW67 = (u16*)take(4 * 4096 * 2);

  hipMemsetAsync(bnrep, 0, (size_t)NREP * 256 * 4, stream);
  k_prep1<<<128, 128, 0, stream>>>(emb, conv_w, conv_b, fuse_w, fuse_b,
                                   fm_w1, g2e_b2, fm_b1, g2e_w2,
                                   Mt, C0, Wnt, b67, W67f);

  PackArgs pa;
  const float* srcs[6] = {g1e_w1, g1e_w2, g1n_w1, g1n_w2, g2e_w1, W67f};
  u16* dsts[6] = {pW1, pW2, pW3, pW4, pW5, pW67};
  int kins[6] = {260, 128, 256, 128, 384, 128};
  int kst[6] = {9, 4, 8, 4, 12, 4};
  int cum = 0;
  for (int i = 0; i < 6; ++i) {
    pa.src[i] = srcs[i]; pa.dst[i] = dsts[i]; pa.Kin[i] = kins[i];
    pa.ksCum[i] = cum; cum += kst[i];
  }
  pa.ksCum[6] = cum;  // 41

  k_prep2<<<41 + N_NODES / 16, 256, 0, stream>>>(pa, x, node_type, Mt, C0, Wnt, h2);
  k_gnn1<<<NBLK, 256, 0, stream>>>(eidx, eattr, h2, pW1, pW2, pW3, pW4,
                                   g1e_b1, g1e_b2, g1n_b1, g1n_b2, ea1z, h3);
  k_gnn2<<<NBLK, 256, 0, stream>>>(eidx, h3, ea1z, pW5, pW67,
                                   g2e_b1, b67, bnrep);
  k_head<<<(N_EDGES + 255) / 256, 256, 0, stream>>>(ea1z, bnrep, bn_g, bn_b,
                                                    fm_w2, fm_b2, out);
}